// Round 5
// baseline (27418.378 us; speedup 1.0000x reference)
//
#include <hip/hip_runtime.h>

// N=512 batch, T=256, H=512, D=9. 257 encode + 256 decode steps, LSTM + fc(sigmoid).
// Persistent kernel: 8 clusters x 32 wgs; cluster owns 64 batch, wg owns 16 hidden units.
// W_hh slice resident in LDS for all steps. Two-phase (batch 32+32) pipelined cluster sync:
// each phase's release/visibility latency hides under the other phase's GEMM.

#define TT 256
#define HH 512
#define DD 9
#define TP1 257
#define NSTEP 513
#define THREADS 512
#define NWG 256
#define NCL 8
#define WPC 32
#define KC 64
#define NC 8

// ws float offsets
#define WP_OFF 0
#define WP_SZ (2048 * 512)              // Wp[wl 32][k 512][r 64]  (4 MB)
#define HT_OFF WP_SZ                    // hT[2][cl 8][k 512][b 64] (2 MB)
#define HT_HALF (NCL * 512 * 64)
#define FLAG_OFF (HT_OFF + 2 * HT_HALF) // u32 flag[2 phase][8 cl][32 wl]

// LDS float offsets (38592 floats = 150.75 KB)
#define L_W 0                           // Wlds[k 512][r 64]  128 KB
#define L_UN 32768                      // union: hbuf[2][KC 64][32] (4096) | gates[64][GSTR 34] (2176)
#define L_C (L_UN + 4096)               // c[u 16][b 64]
#define L_BIAS (L_C + 1024)             // bias[64]
#define L_WIH (L_BIAS + 64)             // wih[64][10]
#define L_TOT (L_WIH + 640)
#define GSTR 34

__device__ __forceinline__ float sigmoidf_(float v) {
    return 1.0f / (1.0f + __expf(-v));
}
__device__ __forceinline__ float tanhf_(float v) {
    return 1.0f - 2.0f / (__expf(2.0f * v) + 1.0f);
}

// Pack Wp[wl][k][r]: r = g*16+u  <->  W_hh[g*512 + wl*16 + u][k].  hT[0] = h0, flags = 0.
__global__ void rnn_init_kernel(const float* __restrict__ W_hh,
                                const float* __restrict__ h0,
                                float* __restrict__ ws) {
    int idx = blockIdx.x * blockDim.x + threadIdx.x;   // 0 .. 2048*512-1
    {
        int r  = idx & 63;
        int k  = (idx >> 6) & 511;
        int wl = idx >> 15;
        int g = r >> 4, u = r & 15;
        int grow = g * 512 + wl * 16 + u;
        ws[WP_OFF + idx] = W_hh[grow * 512 + k];
    }
    if (idx < HT_HALF) {
        int k = (idx >> 6) & 511;
        ws[HT_OFF + idx] = h0[k];
    }
    if (idx < 2 * NCL * WPC) {
        ((unsigned int*)(ws + FLAG_OFF))[idx] = 0u;
    }
}

__global__ __launch_bounds__(THREADS)
void rnn_persist_kernel(const float* __restrict__ x,
                        const float* __restrict__ W_ih,
                        const float* __restrict__ b_ih,
                        const float* __restrict__ b_hh,
                        const float* __restrict__ fc_W,
                        const float* __restrict__ fc_b,
                        const float* __restrict__ c0,
                        float* __restrict__ ws,
                        float* __restrict__ out) {
    __shared__ float smem[L_TOT];

    const int cl  = blockIdx.x & 7;    // cluster (XCD round-robin -> co-located best-effort)
    const int wl  = blockIdx.x >> 3;   // slice within cluster, 0..31
    const int j0  = wl * 16;
    const int nb0 = cl * 64;
    const int tid = threadIdx.x;

    unsigned int* flags = (unsigned int*)(ws + FLAG_OFF);
    float* hT = ws + HT_OFF;

    // ---- one-time: W slice -> LDS, c from c0, bias, wih ----
    {
        const float* wsrc = ws + WP_OFF + wl * (512 * 64);
        for (int i = tid * 4; i < 512 * 64; i += THREADS * 4)
            *(float4*)(smem + L_W + i) = *(const float4*)(wsrc + i);
        int u = tid >> 6;
        smem[L_C + tid]       = c0[j0 + u];
        smem[L_C + 512 + tid] = c0[j0 + 8 + u];
        if (tid < 64) {
            int g = tid >> 4, u2 = tid & 15;
            smem[L_BIAS + tid] = b_ih[g * 512 + wl * 16 + u2] + b_hh[g * 512 + wl * 16 + u2];
        }
        for (int i = tid; i < 64 * DD; i += THREADS) {
            int r = i / DD, d = i - r * DD;
            int g = r >> 4, u2 = r & 15;
            smem[L_WIH + r * 10 + d] = W_ih[(g * 512 + wl * 16 + u2) * DD + d];
        }
    }
    __syncthreads();

    const int tr  = tid & 31;          // gemm rows {2tr, 2tr+1}
    const int tb  = tid >> 5;          // gemm batch {2tb, 2tb+1} within half
    const int sk  = tid >> 3;          // staging k-row within chunk
    const int sb  = (tid & 7) * 4;     // staging batch col
    const int cu  = tid >> 5;          // cell unit 0..15
    const int ccb = tid & 31;          // cell batch within half

    for (int s = 0; s < NSTEP; ++s) {
        const float* hsrc = hT + (s & 1) * HT_HALF + cl * (512 * 64);
        float* hdst = hT + ((s & 1) ^ 1) * HT_HALF + cl * (512 * 64);

        for (int ph = 0; ph < 2; ++ph) {
            unsigned int* flg = flags + (ph * NCL + cl) * WPC;

            // ---- wait: all wgs completed phase ph of step s-1 (signaled >= one phase ago) ----
            if (s > 0) {
                if (tid < WPC) {
                    while (__hip_atomic_load(flg + tid, __ATOMIC_RELAXED,
                                             __HIP_MEMORY_SCOPE_AGENT) < (unsigned)s)
                        __builtin_amdgcn_s_sleep(4);
                }
                __syncthreads();
                __builtin_amdgcn_fence(__ATOMIC_ACQUIRE, "agent");
            }

            // ---- fc output (decode): h(s) of this half is now ready ----
            if (s >= TP1 + 1 && (wl >> 4) == ph) {
                int wq = tid >> 4, l16 = tid & 15;
                if (wq < 2 * DD) {
                    int bsel = wq / DD, d = wq - bsel * DD;
                    int bl = wl * 2 + bsel;           // in [ph*32, ph*32+32)
                    const float* hv2 = hsrc + bl;
                    float acc = 0.f;
#pragma unroll 8
                    for (int k = l16; k < HH; k += 16)
                        acc += hv2[k * 64] * fc_W[d * HH + k];
                    acc += __shfl_down(acc, 8, 16);
                    acc += __shfl_down(acc, 4, 16);
                    acc += __shfl_down(acc, 2, 16);
                    acc += __shfl_down(acc, 1, 16);
                    if (l16 == 0) {
                        int td = s - (TP1 + 1);
                        out[(size_t)(nb0 + bl) * (TT * DD) + td * DD + d] =
                            1.0f / (1.0f + __expf(-(acc + fc_b[d])));
                    }
                }
            }

            // ---- GEMM over half ph: gates[r][b] = sum_k W[r][k] * h[k][ph*32+b] ----
            const float* hph = hsrc + ph * 32;
            float a00 = 0.f, a01 = 0.f, a10 = 0.f, a11 = 0.f;
            float4 rh = *(const float4*)(hph + sk * 64 + sb);
            for (int c = 0; c < NC; ++c) {
                float4 nh;
                if (c + 1 < NC)
                    nh = *(const float4*)(hph + ((c + 1) * KC + sk) * 64 + sb);
                *(float4*)(smem + L_UN + (c & 1) * 2048 + sk * 32 + sb) = rh;
                asm volatile("s_waitcnt lgkmcnt(0)" ::: "memory");
                __builtin_amdgcn_s_barrier();

                const float* hb = smem + L_UN + (c & 1) * 2048 + 2 * tb;
                const float* wb = smem + L_W + (c * KC) * 64 + 2 * tr;
#pragma unroll 16
                for (int k = 0; k < KC; ++k) {
                    float2 hv = *(const float2*)(hb + k * 32);
                    float2 wv = *(const float2*)(wb + k * 64);
                    a00 += hv.x * wv.x; a01 += hv.y * wv.x;
                    a10 += hv.x * wv.y; a11 += hv.y * wv.y;
                }
                rh = nh;
            }
            // union switch hbuf -> gates
            asm volatile("s_waitcnt lgkmcnt(0)" ::: "memory");
            __builtin_amdgcn_s_barrier();
            *(float2*)(smem + L_UN + (2 * tr) * GSTR + 2 * tb)     = make_float2(a00, a01);
            *(float2*)(smem + L_UN + (2 * tr + 1) * GSTR + 2 * tb) = make_float2(a10, a11);
            asm volatile("s_waitcnt lgkmcnt(0)" ::: "memory");
            __builtin_amdgcn_s_barrier();

            // ---- LSTM cell: thread owns unit cu, batch ph*32+ccb ----
            {
                int cbn = ph * 32 + ccb;
                float vi = smem[L_UN + (cu)*GSTR + ccb]      + smem[L_BIAS + cu];
                float vf = smem[L_UN + (16 + cu)*GSTR + ccb] + smem[L_BIAS + 16 + cu];
                float vg = smem[L_UN + (32 + cu)*GSTR + ccb] + smem[L_BIAS + 32 + cu];
                float vo = smem[L_UN + (48 + cu)*GSTR + ccb] + smem[L_BIAS + 48 + cu];
                if (s < TP1) {
                    const float* xp = x + (size_t)(nb0 + cbn) * (TP1 * DD) + s * DD;
                    float xv[DD];
#pragma unroll
                    for (int d = 0; d < DD; ++d) xv[d] = xp[d];
                    float di = 0.f, df = 0.f, dg = 0.f, dq = 0.f;
#pragma unroll
                    for (int d = 0; d < DD; ++d) {
                        di += xv[d] * smem[L_WIH + (cu)*10 + d];
                        df += xv[d] * smem[L_WIH + (16 + cu)*10 + d];
                        dg += xv[d] * smem[L_WIH + (32 + cu)*10 + d];
                        dq += xv[d] * smem[L_WIH + (48 + cu)*10 + d];
                    }
                    vi += di; vf += df; vg += dg; vo += dq;
                }
                float c_old = smem[L_C + cu * 64 + cbn];
                float si = sigmoidf_(vi), sf = sigmoidf_(vf), so = sigmoidf_(vo);
                float tg = tanhf_(vg);
                float cn = sf * c_old + si * tg;
                smem[L_C + cu * 64 + cbn] = cn;
                hdst[(j0 + cu) * 64 + cbn] = so * tanhf_(cn);
            }
            __syncthreads();   // drains vmcnt: this wg's h stores (and fc/gemm loads) complete

            // ---- signal: fire-and-forget release store; visibility hides under next phase ----
            if (tid == 0)
                __hip_atomic_store(flg + wl, (unsigned)(s + 1), __ATOMIC_RELEASE,
                                   __HIP_MEMORY_SCOPE_AGENT);
        }
    }

    // ---- tail fc: td = 255 from h(513) (parity 1) ----
    {
        int ph = wl >> 4;
        unsigned int* flg = flags + (ph * NCL + cl) * WPC;
        if (tid < WPC) {
            while (__hip_atomic_load(flg + tid, __ATOMIC_RELAXED,
                                     __HIP_MEMORY_SCOPE_AGENT) < (unsigned)NSTEP)
                __builtin_amdgcn_s_sleep(4);
        }
        __syncthreads();
        __builtin_amdgcn_fence(__ATOMIC_ACQUIRE, "agent");

        const float* hsrc = hT + (NSTEP & 1) * HT_HALF + cl * (512 * 64);
        int wq = tid >> 4, l16 = tid & 15;
        if (wq < 2 * DD) {
            int bsel = wq / DD, d = wq - bsel * DD;
            int bl = wl * 2 + bsel;
            const float* hv2 = hsrc + bl;
            float acc = 0.f;
#pragma unroll 8
            for (int k = l16; k < HH; k += 16)
                acc += hv2[k * 64] * fc_W[d * HH + k];
            acc += __shfl_down(acc, 8, 16);
            acc += __shfl_down(acc, 4, 16);
            acc += __shfl_down(acc, 2, 16);
            acc += __shfl_down(acc, 1, 16);
            if (l16 == 0)
                out[(size_t)(nb0 + bl) * (TT * DD) + 255 * DD + d] =
                    1.0f / (1.0f + __expf(-(acc + fc_b[d])));
        }
    }
}

extern "C" void kernel_launch(void* const* d_in, const int* in_sizes, int n_in,
                              void* d_out, int out_size, void* d_ws, size_t ws_size,
                              hipStream_t stream) {
    (void)in_sizes; (void)n_in; (void)out_size; (void)ws_size;
    const float* x    = (const float*)d_in[0];
    const float* W_ih = (const float*)d_in[1];
    const float* W_hh = (const float*)d_in[2];
    const float* b_ih = (const float*)d_in[3];
    const float* b_hh = (const float*)d_in[4];
    const float* fc_W = (const float*)d_in[5];
    const float* fc_b = (const float*)d_in[6];
    const float* h0   = (const float*)d_in[7];
    const float* c0   = (const float*)d_in[8];
    float* out = (float*)d_out;
    float* ws  = (float*)d_ws;

    hipLaunchKernelGGL(rnn_init_kernel, dim3(4096), dim3(256), 0, stream,
                       W_hh, h0, ws);
    hipLaunchKernelGGL(rnn_persist_kernel, dim3(NWG), dim3(THREADS), 0, stream,
                       x, W_ih, b_ih, b_hh, fc_W, fc_b, c0, ws, out);
}

// Round 6
// 13430.716 us; speedup vs baseline: 2.0415x; 2.0415x over previous
//
#include <hip/hip_runtime.h>

// N=512 batch, T=256, H=512, D=9. 257 encode + 256 decode steps, LSTM + fc(sigmoid).
// Persistent kernel: 8 clusters x 32 wgs; cluster = blockIdx&7 (one XCD under round-robin
// dispatch, verified at runtime via HW_REG_XCC_ID). Fast path: no agent fences —
// plain stores land in the shared XCD L2 (write-through L1), consumers read via sc0
// (L1-bypass) loads, flags are relaxed agent atomics. Fallback: R4-style agent fences.

#define TT 256
#define HH 512
#define DD 9
#define TP1 257
#define NSTEP 513
#define THREADS 512
#define NWG 256
#define NCL 8
#define WPC 32
#define KC 32
#define NC 16

// ws float offsets
#define WP_OFF   0
#define WP_SZ    (2048 * 512)                 // Wp[wl 32][k 512][r 64]  (4 MB)
#define HT_OFF   WP_SZ                        // hT[2][cl 8][k 512][b 64] (2 MB)
#define HT_HALF  (NCL * 512 * 64)
#define HROW_OFF (HT_OFF + 2 * HT_HALF)       // hrow[2][cl 8][b 64][k 512] (2 MB)
#define HROW_HALF (NCL * 64 * 512)
#define U32_OFF  (HROW_OFF + 2 * HROW_HALF)   // u32: flags[256] | ctr@320 | xcc@384..640

// LDS float offsets (39748 floats = 155.3 KB)
#define L_W    0                              // Wlds[k 512][r 64]  128 KB
#define L_UN   32768                          // union: hbuf[2][32][64] (4096) | gates[64][66]
#define L_C    (L_UN + 4224)                  // c[u 16][b 64]
#define L_BIAS (L_C + 1024)
#define L_WIH  (L_BIAS + 64)                  // wih[64][10]
#define L_HNEW (L_WIH + 640)                  // hnew[u 16][b 64]
#define L_MISC (L_HNEW + 1024)
#define L_TOT  (L_MISC + 4)
#define GSTR 66

typedef float f4 __attribute__((ext_vector_type(4)));

__device__ __forceinline__ float sigmoidf_(float v) {
    return 1.0f / (1.0f + __expf(-v));
}
__device__ __forceinline__ float tanhf_(float v) {
    return 1.0f - 2.0f / (__expf(2.0f * v) + 1.0f);
}

// sc0 load: bypasses L1, reads the XCD-shared L2 (fresh cross-CU data).
__device__ __forceinline__ void ld4_sc0(f4& d, const float* p) {
    asm volatile("global_load_dwordx4 %0, %1, off sc0" : "=v"(d) : "v"(p));
}
__device__ __forceinline__ void wait_vm1(f4& a) {
    asm volatile("s_waitcnt vmcnt(1)" : "+v"(a) :: "memory");
}
__device__ __forceinline__ void wait_vm0_1(f4& a) {
    asm volatile("s_waitcnt vmcnt(0)" : "+v"(a) :: "memory");
}
__device__ __forceinline__ void wait_vm0_8(f4& a0, f4& a1, f4& a2, f4& a3,
                                           f4& a4, f4& a5, f4& a6, f4& a7) {
    asm volatile("s_waitcnt vmcnt(0)"
                 : "+v"(a0), "+v"(a1), "+v"(a2), "+v"(a3),
                   "+v"(a4), "+v"(a5), "+v"(a6), "+v"(a7) :: "memory");
}

// Pack Wp[wl][k][r], r=g*16+u <-> W_hh[g*512+wl*16+u][k]; hT[0]=h0; zero flags/ctr/xcc.
__global__ void rnn_init_kernel(const float* __restrict__ W_hh,
                                const float* __restrict__ h0,
                                float* __restrict__ ws) {
    int idx = blockIdx.x * blockDim.x + threadIdx.x;   // 0 .. 2048*512-1
    {
        int r  = idx & 63;
        int k  = (idx >> 6) & 511;
        int wl = idx >> 15;
        int g = r >> 4, u = r & 15;
        ws[WP_OFF + idx] = W_hh[(g * 512 + wl * 16 + u) * 512 + k];
    }
    if (idx < HT_HALF) {
        int k = (idx >> 6) & 511;
        ws[HT_OFF + idx] = h0[k];
    }
    if (idx < 640) {
        ((unsigned int*)(ws + U32_OFF))[idx] = 0u;
    }
}

__global__ __launch_bounds__(THREADS)
void rnn_persist_kernel(const float* __restrict__ x,
                        const float* __restrict__ W_ih,
                        const float* __restrict__ b_ih,
                        const float* __restrict__ b_hh,
                        const float* __restrict__ fc_W,
                        const float* __restrict__ fc_b,
                        const float* __restrict__ c0,
                        float* __restrict__ ws,
                        float* __restrict__ out) {
    __shared__ float smem[L_TOT];

    const int wg  = blockIdx.x;
    const int cl  = wg & 7;
    const int wl  = wg >> 3;
    const int j0  = wl * 16;
    const int nb0 = cl * 64;
    const int tid = threadIdx.x;

    unsigned int* u32p  = (unsigned int*)(ws + U32_OFF);
    unsigned int* flags = u32p;           // [cl*32 + wl]
    unsigned int* ctr   = u32p + 320;
    unsigned int* xccb  = u32p + 384;     // [wg]
    float* hT = ws + HT_OFF;

    // ---- one-time: W slice -> LDS, c from c0, bias, wih ----
    {
        const float* wsrc = ws + WP_OFF + wl * (512 * 64);
        for (int i = tid * 4; i < 512 * 64; i += THREADS * 4)
            *(f4*)(smem + L_W + i) = *(const f4*)(wsrc + i);
        int u = tid >> 6;
        smem[L_C + tid]       = c0[j0 + u];
        smem[L_C + 512 + tid] = c0[j0 + 8 + u];
        if (tid < 64) {
            int g = tid >> 4, u2 = tid & 15;
            smem[L_BIAS + tid] = b_ih[g * 512 + wl * 16 + u2] + b_hh[g * 512 + wl * 16 + u2];
        }
        for (int i = tid; i < 64 * DD; i += THREADS) {
            int r = i / DD, d = i - r * DD;
            int g = r >> 4, u2 = r & 15;
            smem[L_WIH + r * 10 + d] = W_ih[(g * 512 + wl * 16 + u2) * DD + d];
        }
    }

    // ---- startup: publish XCD id, grid barrier, check cluster co-location ----
    if (tid == 0) {
        unsigned xcc;
        asm volatile("s_getreg_b32 %0, hwreg(HW_REG_XCC_ID, 0, 32)" : "=s"(xcc));
        __hip_atomic_store(xccb + wg, xcc + 1u, __ATOMIC_RELAXED, __HIP_MEMORY_SCOPE_AGENT);
        __hip_atomic_fetch_add(ctr, 1u, __ATOMIC_RELEASE, __HIP_MEMORY_SCOPE_AGENT);
        while (__hip_atomic_load(ctr, __ATOMIC_RELAXED, __HIP_MEMORY_SCOPE_AGENT) < NWG)
            __builtin_amdgcn_s_sleep(8);
    }
    __syncthreads();
    {
        unsigned v = (tid < WPC)
            ? __hip_atomic_load(xccb + tid * NCL + cl, __ATOMIC_RELAXED,
                                __HIP_MEMORY_SCOPE_AGENT)
            : 0u;
        unsigned v0 = __shfl(v, 0, 64);
        bool ok = (tid >= WPC) || (v != 0u && v == v0);
        unsigned long long m = __ballot(ok);
        if (tid == 0) smem[L_MISC] = (m == ~0ull) ? 1.0f : 0.0f;
    }
    __syncthreads();
    const bool fast = (smem[L_MISC] != 0.0f);

    const int tr = tid & 15;           // gemm rows 4tr..4tr+3
    const int tb = tid >> 4;           // gemm batch {2tb, 2tb+1}
    const int sk = tid >> 4;           // staging k-row (0..31)
    const int sb = (tid & 15) * 4;     // staging batch col
    const int cw = tid >> 6;           // cell: units {cw, cw+8}
    const int cb = tid & 63;           // cell: batch

    for (int s = 0; s < NSTEP; ++s) {
        const int par = s & 1;
        const float* hsrc = hT + par * HT_HALF + cl * (512 * 64);
        float* hdst = hT + (par ^ 1) * HT_HALF + cl * (512 * 64);

        // ---- 1. wait: all wgs finished step s-1 ----
        if (s > 0) {
            if (tid < WPC) {
                for (;;) {
                    unsigned v = __hip_atomic_load(flags + cl * WPC + tid,
                                                   __ATOMIC_RELAXED, __HIP_MEMORY_SCOPE_AGENT);
                    if (__all((int)(v >= (unsigned)s))) break;
                    __builtin_amdgcn_s_sleep(1);
                }
            }
            __syncthreads();
            if (fast) __builtin_amdgcn_fence(__ATOMIC_ACQUIRE, "workgroup");
            else      __builtin_amdgcn_fence(__ATOMIC_ACQUIRE, "agent");
        }

        // ---- 2. fc output for h(s) (decode): out[:, s-258, :] ----
        if (s >= TP1 + 1) {
            const int fg = tid >> 4, fl = tid & 15;
            if (fg < 2 * DD) {
                const int bsel = fg / DD, d = fg - bsel * DD;
                const int bl = wl * 2 + bsel;
                const float* hp = ws + HROW_OFF + par * HROW_HALF + cl * (64 * 512)
                                  + bl * 512 + fl * 32;
                f4 q0, q1, q2, q3, q4, q5, q6, q7;
                ld4_sc0(q0, hp);      ld4_sc0(q1, hp + 4);
                ld4_sc0(q2, hp + 8);  ld4_sc0(q3, hp + 12);
                ld4_sc0(q4, hp + 16); ld4_sc0(q5, hp + 20);
                ld4_sc0(q6, hp + 24); ld4_sc0(q7, hp + 28);
                const f4* wv = (const f4*)(fc_W + d * HH + fl * 32);
                wait_vm0_8(q0, q1, q2, q3, q4, q5, q6, q7);
                float acc = 0.f;
                acc += q0.x*wv[0].x + q0.y*wv[0].y + q0.z*wv[0].z + q0.w*wv[0].w;
                acc += q1.x*wv[1].x + q1.y*wv[1].y + q1.z*wv[1].z + q1.w*wv[1].w;
                acc += q2.x*wv[2].x + q2.y*wv[2].y + q2.z*wv[2].z + q2.w*wv[2].w;
                acc += q3.x*wv[3].x + q3.y*wv[3].y + q3.z*wv[3].z + q3.w*wv[3].w;
                acc += q4.x*wv[4].x + q4.y*wv[4].y + q4.z*wv[4].z + q4.w*wv[4].w;
                acc += q5.x*wv[5].x + q5.y*wv[5].y + q5.z*wv[5].z + q5.w*wv[5].w;
                acc += q6.x*wv[6].x + q6.y*wv[6].y + q6.z*wv[6].z + q6.w*wv[6].w;
                acc += q7.x*wv[7].x + q7.y*wv[7].y + q7.z*wv[7].z + q7.w*wv[7].w;
                acc += __shfl_down(acc, 8, 16);
                acc += __shfl_down(acc, 4, 16);
                acc += __shfl_down(acc, 2, 16);
                acc += __shfl_down(acc, 1, 16);
                if (fl == 0)
                    out[(size_t)(nb0 + bl) * (TT * DD) + (s - (TP1 + 1)) * DD + d] =
                        1.0f / (1.0f + __expf(-(acc + fc_b[d])));
            }
        }

        // ---- 3. x prefetch for the cell (encode only) ----
        float xv[DD];
        if (s < TP1) {
            const float* xp = x + (size_t)(nb0 + cb) * (TP1 * DD) + s * DD;
#pragma unroll
            for (int d = 0; d < DD; ++d) xv[d] = xp[d];
        }

        // ---- 4. GEMM: gates[r][b] = sum_k W[k][r] * h[k][b], sc0-prefetched staging ----
        float a00 = 0.f, a01 = 0.f, a10 = 0.f, a11 = 0.f;
        float a20 = 0.f, a21 = 0.f, a30 = 0.f, a31 = 0.f;
        {
            const float* sp = hsrc + sk * 64 + sb;
            f4 cur, nxt;
            ld4_sc0(cur, sp);
            for (int c = 0; c < NC; ++c) {
                if (c + 1 < NC) {
                    ld4_sc0(nxt, sp + (c + 1) * (KC * 64));
                    wait_vm1(cur);
                } else {
                    wait_vm0_1(cur);
                }
                *(f4*)(smem + L_UN + (c & 1) * 2048 + sk * 64 + sb) = cur;
                asm volatile("s_waitcnt lgkmcnt(0)" ::: "memory");
                __builtin_amdgcn_s_barrier();

                const float* wb = smem + L_W + (c * KC) * 64 + 4 * tr;
                const float* hb = smem + L_UN + (c & 1) * 2048 + 2 * tb;
#pragma unroll
                for (int k = 0; k < KC; ++k) {
                    f4     wv2 = *(const f4*)(wb + k * 64);
                    float2 hv  = *(const float2*)(hb + k * 64);
                    a00 += wv2.x * hv.x; a01 += wv2.x * hv.y;
                    a10 += wv2.y * hv.x; a11 += wv2.y * hv.y;
                    a20 += wv2.z * hv.x; a21 += wv2.z * hv.y;
                    a30 += wv2.w * hv.x; a31 += wv2.w * hv.y;
                }
                cur = nxt;
            }
        }

        // ---- 5. union switch: hbuf -> gates ----
        asm volatile("s_waitcnt lgkmcnt(0)" ::: "memory");
        __builtin_amdgcn_s_barrier();
        {
            float* gp = smem + L_UN + (4 * tr) * GSTR + 2 * tb;
            *(float2*)(gp)            = make_float2(a00, a01);
            *(float2*)(gp + GSTR)     = make_float2(a10, a11);
            *(float2*)(gp + 2 * GSTR) = make_float2(a20, a21);
            *(float2*)(gp + 3 * GSTR) = make_float2(a30, a31);
        }
        asm volatile("s_waitcnt lgkmcnt(0)" ::: "memory");
        __builtin_amdgcn_s_barrier();

        // ---- 6. LSTM cell: units {cw, cw+8}, batch cb ----
        {
#pragma unroll
            for (int half = 0; half < 2; ++half) {
                const int u = cw + half * 8;
                float vi = smem[L_UN + (u) * GSTR + cb]      + smem[L_BIAS + u];
                float vf = smem[L_UN + (16 + u) * GSTR + cb] + smem[L_BIAS + 16 + u];
                float vg = smem[L_UN + (32 + u) * GSTR + cb] + smem[L_BIAS + 32 + u];
                float vo = smem[L_UN + (48 + u) * GSTR + cb] + smem[L_BIAS + 48 + u];
                if (s < TP1) {
                    float di = 0.f, df = 0.f, dg = 0.f, dq = 0.f;
#pragma unroll
                    for (int d = 0; d < DD; ++d) {
                        di += xv[d] * smem[L_WIH + (u) * 10 + d];
                        df += xv[d] * smem[L_WIH + (16 + u) * 10 + d];
                        dg += xv[d] * smem[L_WIH + (32 + u) * 10 + d];
                        dq += xv[d] * smem[L_WIH + (48 + u) * 10 + d];
                    }
                    vi += di; vf += df; vg += dg; vo += dq;
                }
                float c_old = smem[L_C + u * 64 + cb];
                float si = sigmoidf_(vi), sf = sigmoidf_(vf), so = sigmoidf_(vo);
                float tg = tanhf_(vg);
                float cn = sf * c_old + si * tg;
                smem[L_C + u * 64 + cb] = cn;
                float hn = so * tanhf_(cn);
                smem[L_HNEW + u * 64 + cb] = hn;
                hdst[(j0 + u) * 64 + cb] = hn;
            }
        }
        asm volatile("s_waitcnt lgkmcnt(0)" ::: "memory");
        __builtin_amdgcn_s_barrier();

        // ---- 7. hrow remap (row-major h for fc) ----
        {
            float* hrp = ws + HROW_OFF + (par ^ 1) * HROW_HALF + cl * (64 * 512);
            const int kl = tid & 15, nl0 = tid >> 4;
#pragma unroll
            for (int i = 0; i < 2; ++i) {
                const int nl = nl0 + i * 32;
                hrp[nl * 512 + j0 + kl] = smem[L_HNEW + kl * 64 + nl];
            }
        }
        asm volatile("s_waitcnt vmcnt(0)" ::: "memory");
        __syncthreads();

        // ---- 8. signal ----
        if (tid == 0) {
            if (fast) {
                __hip_atomic_store(flags + cl * WPC + wl, (unsigned)(s + 1),
                                   __ATOMIC_RELAXED, __HIP_MEMORY_SCOPE_AGENT);
            } else {
                __builtin_amdgcn_fence(__ATOMIC_RELEASE, "agent");
                __hip_atomic_store(flags + cl * WPC + wl, (unsigned)(s + 1),
                                   __ATOMIC_RELEASE, __HIP_MEMORY_SCOPE_AGENT);
            }
        }
    }

    // ---- tail fc: td = 255 from h(513) ----
    {
        if (tid < WPC) {
            for (;;) {
                unsigned v = __hip_atomic_load(flags + cl * WPC + tid,
                                               __ATOMIC_RELAXED, __HIP_MEMORY_SCOPE_AGENT);
                if (__all((int)(v >= (unsigned)NSTEP))) break;
                __builtin_amdgcn_s_sleep(1);
            }
        }
        __syncthreads();
        if (fast) __builtin_amdgcn_fence(__ATOMIC_ACQUIRE, "workgroup");
        else      __builtin_amdgcn_fence(__ATOMIC_ACQUIRE, "agent");

        const int fg = tid >> 4, fl = tid & 15;
        if (fg < 2 * DD) {
            const int bsel = fg / DD, d = fg - bsel * DD;
            const int bl = wl * 2 + bsel;
            const float* hp = ws + HROW_OFF + (NSTEP & 1) * HROW_HALF + cl * (64 * 512)
                              + bl * 512 + fl * 32;
            f4 q0, q1, q2, q3, q4, q5, q6, q7;
            ld4_sc0(q0, hp);      ld4_sc0(q1, hp + 4);
            ld4_sc0(q2, hp + 8);  ld4_sc0(q3, hp + 12);
            ld4_sc0(q4, hp + 16); ld4_sc0(q5, hp + 20);
            ld4_sc0(q6, hp + 24); ld4_sc0(q7, hp + 28);
            const f4* wv = (const f4*)(fc_W + d * HH + fl * 32);
            wait_vm0_8(q0, q1, q2, q3, q4, q5, q6, q7);
            float acc = 0.f;
            acc += q0.x*wv[0].x + q0.y*wv[0].y + q0.z*wv[0].z + q0.w*wv[0].w;
            acc += q1.x*wv[1].x + q1.y*wv[1].y + q1.z*wv[1].z + q1.w*wv[1].w;
            acc += q2.x*wv[2].x + q2.y*wv[2].y + q2.z*wv[2].z + q2.w*wv[2].w;
            acc += q3.x*wv[3].x + q3.y*wv[3].y + q3.z*wv[3].z + q3.w*wv[3].w;
            acc += q4.x*wv[4].x + q4.y*wv[4].y + q4.z*wv[4].z + q4.w*wv[4].w;
            acc += q5.x*wv[5].x + q5.y*wv[5].y + q5.z*wv[5].z + q5.w*wv[5].w;
            acc += q6.x*wv[6].x + q6.y*wv[6].y + q6.z*wv[6].z + q6.w*wv[6].w;
            acc += q7.x*wv[7].x + q7.y*wv[7].y + q7.z*wv[7].z + q7.w*wv[7].w;
            acc += __shfl_down(acc, 8, 16);
            acc += __shfl_down(acc, 4, 16);
            acc += __shfl_down(acc, 2, 16);
            acc += __shfl_down(acc, 1, 16);
            if (fl == 0)
                out[(size_t)(nb0 + bl) * (TT * DD) + 255 * DD + d] =
                    1.0f / (1.0f + __expf(-(acc + fc_b[d])));
        }
    }
}

extern "C" void kernel_launch(void* const* d_in, const int* in_sizes, int n_in,
                              void* d_out, int out_size, void* d_ws, size_t ws_size,
                              hipStream_t stream) {
    (void)in_sizes; (void)n_in; (void)out_size; (void)ws_size;
    const float* x    = (const float*)d_in[0];
    const float* W_ih = (const float*)d_in[1];
    const float* W_hh = (const float*)d_in[2];
    const float* b_ih = (const float*)d_in[3];
    const float* b_hh = (const float*)d_in[4];
    const float* fc_W = (const float*)d_in[5];
    const float* fc_b = (const float*)d_in[6];
    const float* h0   = (const float*)d_in[7];
    const float* c0   = (const float*)d_in[8];
    float* out = (float*)d_out;
    float* ws  = (float*)d_ws;

    hipLaunchKernelGGL(rnn_init_kernel, dim3(4096), dim3(256), 0, stream,
                       W_hh, h0, ws);
    hipLaunchKernelGGL(rnn_persist_kernel, dim3(NWG), dim3(THREADS), 0, stream,
                       x, W_ih, b_ih, b_hh, fc_W, fc_b, c0, ws, out);
}

// Round 7
// 6025.662 us; speedup vs baseline: 4.5503x; 2.2289x over previous
//
#include <hip/hip_runtime.h>

// N=512 batch, T=256, H=512, D=9. 257 encode + 256 decode steps, LSTM + fc(sigmoid).
// Persistent kernel, 8 clusters x 32 wgs (cluster = blockIdx&7 -> one XCD, runtime-verified).
// GEMM via mfma_f32_16x16x32_bf16 with bf16 hi/lo split (3-term) for fp32-grade accuracy.
// W_hh fragments register-resident (invariant across steps). h exchanged through XCD-local
// L2 as pre-packed bf16 fragments; fine-grained per-chunk producer polls (relaxed atomics).

#define TT 256
#define HH 512
#define DD 9
#define TP1 257
#define NSTEP 513
#define THREADS 512
#define NWG 256
#define NCL 8
#define WPC 32
#define GSTR 66

// ws byte offsets
#define WF_HI_B 0u          // Wfrag hi: [wl32][rb4][kt16][lane64][i8] bf16 = 2 MB
#define WF_LO_B 2097152u    // Wfrag lo: 2 MB
#define HFRAG_B 4194304u    // hfrag: [par2][cl8] x 131072 B ([kt16][arr2][g4][col64][i8] bf16)
#define HROW_B  6291456u    // hrow:  [par2][cl8] x 131072 B ([col64][k512] f32)
#define U32_B   8388608u    // flags[256] @0 | ctr @1280 | xcc[256] @1536

// LDS float offsets (15172 floats = 59.3 KB)
#define L_CH    0           // chunk bufs: 2 dbuf x 16384 B = 8192 floats
#define L_GATES 8192        // gates[64][GSTR]
#define L_C     12416       // c[u16][b64]
#define L_BIAS  13440
#define L_WIH   13504       // wih[64][10]
#define L_HNEW  14144       // hnew[u16][b64]
#define L_MISC  15168
#define L_TOT   15172

typedef short s8v __attribute__((ext_vector_type(8)));
typedef float f4v __attribute__((ext_vector_type(4)));
typedef int   i4v __attribute__((ext_vector_type(4)));

__device__ __forceinline__ float sigmoidf_(float v){ return 1.0f/(1.0f+__expf(-v)); }
__device__ __forceinline__ float tanhf_(float v){ return 1.0f - 2.0f/(__expf(2.0f*v)+1.0f); }
__device__ __forceinline__ unsigned short bf16hi_rne(float f){
    unsigned u = __float_as_uint(f);
    return (unsigned short)((u + 0x7fffu + ((u>>16)&1u)) >> 16);
}

__device__ __forceinline__ void ld16i(i4v& d, const char* p){
    asm volatile("global_load_dwordx4 %0, %1, off sc0" : "=v"(d) : "v"(p));
}
__device__ __forceinline__ void ld16f(f4v& d, const char* p){
    asm volatile("global_load_dwordx4 %0, %1, off sc0" : "=v"(d) : "v"(p));
}
__device__ __forceinline__ void wait_vm2_i(i4v& a, i4v& b){
    asm volatile("s_waitcnt vmcnt(2)" : "+v"(a), "+v"(b) :: "memory");
}
__device__ __forceinline__ void wait_vm0_i(i4v& a, i4v& b){
    asm volatile("s_waitcnt vmcnt(0)" : "+v"(a), "+v"(b) :: "memory");
}
__device__ __forceinline__ void wait_vm0_8i(i4v& a0,i4v& a1,i4v& a2,i4v& a3,
                                            i4v& a4,i4v& a5,i4v& a6,i4v& a7){
    asm volatile("s_waitcnt vmcnt(0)"
                 : "+v"(a0),"+v"(a1),"+v"(a2),"+v"(a3),
                   "+v"(a4),"+v"(a5),"+v"(a6),"+v"(a7) :: "memory");
}
__device__ __forceinline__ void wait_vm0_8f(f4v& a0,f4v& a1,f4v& a2,f4v& a3,
                                            f4v& a4,f4v& a5,f4v& a6,f4v& a7){
    asm volatile("s_waitcnt vmcnt(0)"
                 : "+v"(a0),"+v"(a1),"+v"(a2),"+v"(a3),
                   "+v"(a4),"+v"(a5),"+v"(a6),"+v"(a7) :: "memory");
}

// init: pack W_hh into A-fragments (hi/lo), h0 into hfrag[par=0], zero flags.
__global__ void rnn_init_kernel(const float* __restrict__ W_hh,
                                const float* __restrict__ h0,
                                char* __restrict__ wsb) {
    int idx = blockIdx.x * blockDim.x + threadIdx.x;   // 0 .. 1048575
    {
        int i  = idx & 7;
        int l  = (idx >> 3) & 63;
        int kt = (idx >> 9) & 15;
        int rb = (idx >> 13) & 3;
        int wl = idx >> 15;
        int m = l & 15, g = l >> 4;
        int grow = rb * 512 + wl * 16 + m;
        int k = kt * 32 + g * 8 + i;
        float v = W_hh[grow * 512 + k];
        unsigned short hi = bf16hi_rne(v);
        float fh = __uint_as_float(((unsigned)hi) << 16);
        unsigned short lo = bf16hi_rne(v - fh);
        ((unsigned short*)(wsb + WF_HI_B))[idx] = hi;
        ((unsigned short*)(wsb + WF_LO_B))[idx] = lo;
    }
    if (idx < 524288) {   // hfrag par 0: [cl8][kt16][arr2][g4][col64][i8]
        int i   = idx & 7;
        int g   = (idx >> 9) & 3;
        int arr = (idx >> 11) & 1;
        int kt  = (idx >> 12) & 15;
        int cl  = idx >> 16;
        int rem = idx & 65535;
        int j = kt * 32 + g * 8 + i;
        float v = h0[j];
        unsigned short hi = bf16hi_rne(v);
        unsigned short w = hi;
        if (arr) {
            float fh = __uint_as_float(((unsigned)hi) << 16);
            w = bf16hi_rne(v - fh);
        }
        ((unsigned short*)(wsb + HFRAG_B + cl * 131072u))[rem] = w;
    }
    if (idx < 640) ((unsigned int*)(wsb + U32_B))[idx] = 0u;
}

__global__ __launch_bounds__(THREADS)
void rnn_persist_kernel(const float* __restrict__ x,
                        const float* __restrict__ W_ih,
                        const float* __restrict__ b_ih,
                        const float* __restrict__ b_hh,
                        const float* __restrict__ fc_W,
                        const float* __restrict__ fc_b,
                        const float* __restrict__ c0,
                        char* __restrict__ wsb,
                        float* __restrict__ out) {
    __shared__ float smem[L_TOT];
    char* ldsch = (char*)smem;          // chunk bufs at byte 0

    const int wg  = blockIdx.x;
    const int cl  = wg & 7;
    const int wl  = wg >> 3;
    const int j0  = wl * 16;
    const int nb0 = cl * 64;
    const int tid = threadIdx.x;
    const int lane = tid & 63;
    const int wid  = tid >> 6;
    const int rb   = wid & 3;           // row-tile (gate) of this wave
    const int cbh  = wid >> 2;          // batch half (0/1)
    const int m    = lane & 15;
    const int g    = lane >> 4;

    unsigned int* flags = (unsigned int*)(wsb + U32_B);        // [cl*32 + wl]
    unsigned int* ctr   = (unsigned int*)(wsb + U32_B + 1280);
    unsigned int* xccb  = (unsigned int*)(wsb + U32_B + 1536); // [wg]

    // ---- one-time: constants to LDS ----
    {
        int u = tid >> 6;
        smem[L_C + tid]       = c0[j0 + u];
        smem[L_C + 512 + tid] = c0[j0 + 8 + u];
        if (tid < 64) {
            int gt = tid >> 4, u2 = tid & 15;
            smem[L_BIAS + tid] = b_ih[gt*512 + wl*16 + u2] + b_hh[gt*512 + wl*16 + u2];
        }
        for (int i = tid; i < 64 * DD; i += THREADS) {
            int r = i / DD, d = i - r * DD;
            int gt = r >> 4, u2 = r & 15;
            smem[L_WIH + r * 10 + d] = W_ih[(gt*512 + wl*16 + u2) * DD + d];
        }
    }

    // ---- one-time: W A-fragments into registers (hi + lo) ----
    s8v wAh[16], wAl[16];
    {
        const char* base = wsb + (unsigned)(((wl*4 + rb)*16)*64 + lane)*16u;
#pragma unroll
        for (int kt = 0; kt < 16; ++kt) {
            wAh[kt] = *(const s8v*)(base + WF_HI_B + kt*1024);
            wAl[kt] = *(const s8v*)(base + WF_LO_B + kt*1024);
        }
    }

    // ---- startup: publish XCD id, grid barrier, co-location check ----
    if (tid == 0) {
        unsigned xcc;
        asm volatile("s_getreg_b32 %0, hwreg(HW_REG_XCC_ID, 0, 32)" : "=s"(xcc));
        __hip_atomic_store(xccb + wg, xcc + 1u, __ATOMIC_RELAXED, __HIP_MEMORY_SCOPE_AGENT);
        __hip_atomic_fetch_add(ctr, 1u, __ATOMIC_RELEASE, __HIP_MEMORY_SCOPE_AGENT);
        while (__hip_atomic_load(ctr, __ATOMIC_RELAXED, __HIP_MEMORY_SCOPE_AGENT) < NWG)
            __builtin_amdgcn_s_sleep(8);
    }
    __syncthreads();
    {
        unsigned v = (tid < WPC)
            ? __hip_atomic_load(xccb + tid * NCL + cl, __ATOMIC_RELAXED,
                                __HIP_MEMORY_SCOPE_AGENT) : 0u;
        unsigned v0 = __shfl(v, 0, 64);
        bool ok = (tid >= WPC) || (v != 0u && v == v0);
        unsigned long long mk = __ballot(ok);
        if (tid == 0) smem[L_MISC] = (mk == ~0ull) ? 1.0f : 0.0f;
    }
    __syncthreads();
    const bool fast = (smem[L_MISC] != 0.0f);

    const int cw = tid >> 6;           // cell: units {cw, cw+8}
    const int cb = tid & 63;           // cell: batch

    for (int s = 0; s < NSTEP; ++s) {
        const int par = s & 1;
        const char* hsrc = wsb + HFRAG_B + (unsigned)(par*8 + cl) * 131072u;
        unsigned int* flg = flags + cl * 32;

        // ---- step-start: one-shot all-32 flag check (skip fine polls if ready) ----
        bool allready = true;
        if (s > 0) {
            if (fast) {
                const char* fb = (const char*)flg;
                i4v a0,a1,a2,a3,a4,a5,a6,a7;
                ld16i(a0, fb);      ld16i(a1, fb+16);  ld16i(a2, fb+32);  ld16i(a3, fb+48);
                ld16i(a4, fb+64);   ld16i(a5, fb+80);  ld16i(a6, fb+96);  ld16i(a7, fb+112);
                wait_vm0_8i(a0,a1,a2,a3,a4,a5,a6,a7);
                unsigned mn = 0xffffffffu;
#define MN4(A) mn = min(mn,(unsigned)A.x); mn = min(mn,(unsigned)A.y); \
               mn = min(mn,(unsigned)A.z); mn = min(mn,(unsigned)A.w);
                MN4(a0) MN4(a1) MN4(a2) MN4(a3) MN4(a4) MN4(a5) MN4(a6) MN4(a7)
#undef MN4
                allready = (mn >= (unsigned)s);
            } else {
                allready = false;
            }
        }
        __builtin_amdgcn_fence(__ATOMIC_ACQUIRE, "workgroup");

        // ---- x prefetch (encode) ----
        float xv[DD];
        if (s < TP1) {
            const float* xp = x + (size_t)(nb0 + cb) * (TP1 * DD) + s * DD;
#pragma unroll
            for (int d = 0; d < DD; ++d) xv[d] = xp[d];
        }

        // ---- GEMM: 8 chunks (2 kt each), per-thread producer polls, MFMA ----
        f4v acc0 = {0.f,0.f,0.f,0.f}, acc1 = {0.f,0.f,0.f,0.f};
        {
            i4v cur0, cur1, nxt0, nxt1;
            // poll producers of chunk 0 (this thread's slice only)
            if (s > 0 && !allready) {
                volatile unsigned int* f0 = flg + 0 + (g >> 1);
                volatile unsigned int* f1 = f0 + 2;
                while (__hip_atomic_load((unsigned int*)f0, __ATOMIC_RELAXED, __HIP_MEMORY_SCOPE_AGENT) < (unsigned)s ||
                       __hip_atomic_load((unsigned int*)f1, __ATOMIC_RELAXED, __HIP_MEMORY_SCOPE_AGENT) < (unsigned)s)
                    __builtin_amdgcn_s_sleep(1);
                if (!fast) __builtin_amdgcn_fence(__ATOMIC_ACQUIRE, "agent");
            }
            ld16i(cur0, hsrc + 0*8192 + tid*16);
            ld16i(cur1, hsrc + 1*8192 + tid*16);
#pragma unroll
            for (int c = 0; c < 8; ++c) {
                if (c < 7) {
                    if (s > 0 && !allready) {
                        volatile unsigned int* f0 = flg + 4*(c+1) + (g >> 1);
                        volatile unsigned int* f1 = f0 + 2;
                        while (__hip_atomic_load((unsigned int*)f0, __ATOMIC_RELAXED, __HIP_MEMORY_SCOPE_AGENT) < (unsigned)s ||
                               __hip_atomic_load((unsigned int*)f1, __ATOMIC_RELAXED, __HIP_MEMORY_SCOPE_AGENT) < (unsigned)s)
                            __builtin_amdgcn_s_sleep(1);
                        if (!fast) __builtin_amdgcn_fence(__ATOMIC_ACQUIRE, "agent");
                    }
                    ld16i(nxt0, hsrc + (2*c+2)*8192 + tid*16);
                    ld16i(nxt1, hsrc + (2*c+3)*8192 + tid*16);
                    wait_vm2_i(cur0, cur1);
                } else {
                    wait_vm0_i(cur0, cur1);
                }
                *(i4v*)(ldsch + (c&1)*16384 + 0*8192 + tid*16) = cur0;
                *(i4v*)(ldsch + (c&1)*16384 + 1*8192 + tid*16) = cur1;
                asm volatile("s_waitcnt lgkmcnt(0)" ::: "memory");
                __builtin_amdgcn_s_barrier();
#pragma unroll
                for (int j = 0; j < 2; ++j) {
                    const int kt = 2*c + j;
                    const char* bb = ldsch + (c&1)*16384 + j*8192;
                    const int colb = (cbh*32 + m) * 16;
                    s8v bh0 = *(const s8v*)(bb + g*1024        + colb);
                    s8v bh1 = *(const s8v*)(bb + g*1024        + colb + 256);
                    s8v bl0 = *(const s8v*)(bb + 4096 + g*1024 + colb);
                    s8v bl1 = *(const s8v*)(bb + 4096 + g*1024 + colb + 256);
                    acc0 = __builtin_amdgcn_mfma_f32_16x16x32_bf16(wAh[kt], bh0, acc0, 0,0,0);
                    acc1 = __builtin_amdgcn_mfma_f32_16x16x32_bf16(wAh[kt], bh1, acc1, 0,0,0);
                    acc0 = __builtin_amdgcn_mfma_f32_16x16x32_bf16(wAl[kt], bh0, acc0, 0,0,0);
                    acc1 = __builtin_amdgcn_mfma_f32_16x16x32_bf16(wAl[kt], bh1, acc1, 0,0,0);
                    acc0 = __builtin_amdgcn_mfma_f32_16x16x32_bf16(wAh[kt], bl0, acc0, 0,0,0);
                    acc1 = __builtin_amdgcn_mfma_f32_16x16x32_bf16(wAh[kt], bl1, acc1, 0,0,0);
                }
                cur0 = nxt0; cur1 = nxt1;
            }
        }

        // ---- acc -> gates LDS (C/D map: row = 4*g + r, col = m; verified m89/m91) ----
        {
            float* gp = smem + L_GATES + (rb*16 + g*4) * GSTR + cbh*32 + m;
            gp[0*GSTR]      = acc0.x; gp[1*GSTR]      = acc0.y;
            gp[2*GSTR]      = acc0.z; gp[3*GSTR]      = acc0.w;
            gp[0*GSTR + 16] = acc1.x; gp[1*GSTR + 16] = acc1.y;
            gp[2*GSTR + 16] = acc1.z; gp[3*GSTR + 16] = acc1.w;
        }
        asm volatile("s_waitcnt lgkmcnt(0)" ::: "memory");
        __builtin_amdgcn_s_barrier();

        // ---- LSTM cell: units {cw, cw+8}, batch cb ----
        {
#pragma unroll
            for (int half = 0; half < 2; ++half) {
                const int u = cw + half * 8;
                float vi = smem[L_GATES + (u) * GSTR + cb]      + smem[L_BIAS + u];
                float vf = smem[L_GATES + (16 + u) * GSTR + cb] + smem[L_BIAS + 16 + u];
                float vg = smem[L_GATES + (32 + u) * GSTR + cb] + smem[L_BIAS + 32 + u];
                float vo = smem[L_GATES + (48 + u) * GSTR + cb] + smem[L_BIAS + 48 + u];
                if (s < TP1) {
                    float di = 0.f, df = 0.f, dg = 0.f, dq = 0.f;
#pragma unroll
                    for (int d = 0; d < DD; ++d) {
                        di += xv[d] * smem[L_WIH + (u) * 10 + d];
                        df += xv[d] * smem[L_WIH + (16 + u) * 10 + d];
                        dg += xv[d] * smem[L_WIH + (32 + u) * 10 + d];
                        dq += xv[d] * smem[L_WIH + (48 + u) * 10 + d];
                    }
                    vi += di; vf += df; vg += dg; vo += dq;
                }
                float c_old = smem[L_C + u * 64 + cb];
                float si = sigmoidf_(vi), sf = sigmoidf_(vf), so = sigmoidf_(vo);
                float tg = tanhf_(vg);
                float cn = sf * c_old + si * tg;
                smem[L_C + u * 64 + cb] = cn;
                smem[L_HNEW + u * 64 + cb] = so * tanhf_(cn);
            }
        }
        asm volatile("s_waitcnt lgkmcnt(0)" ::: "memory");
        __builtin_amdgcn_s_barrier();

        // ---- fc output for h(s) (decode): out[:, s-258, :]; all-32 dep certified by chunk polls ----
        if (s >= TP1 + 1) {
            const int fg = tid >> 4, fl = tid & 15;
            if (fg < 2 * DD) {
                const int bsel = fg / DD, d = fg - bsel * DD;
                const int bl = wl * 2 + bsel;
                const char* hp = wsb + HROW_B + (unsigned)(par*8 + cl)*131072u
                                 + (unsigned)(bl*512 + fl*32)*4u;
                f4v q0,q1,q2,q3,q4,q5,q6,q7;
                ld16f(q0, hp);      ld16f(q1, hp+16);  ld16f(q2, hp+32);  ld16f(q3, hp+48);
                ld16f(q4, hp+64);   ld16f(q5, hp+80);  ld16f(q6, hp+96);  ld16f(q7, hp+112);
                const f4v* wv = (const f4v*)(fc_W + d * HH + fl * 32);
                wait_vm0_8f(q0,q1,q2,q3,q4,q5,q6,q7);
                float acc = 0.f;
                acc += q0.x*wv[0].x + q0.y*wv[0].y + q0.z*wv[0].z + q0.w*wv[0].w;
                acc += q1.x*wv[1].x + q1.y*wv[1].y + q1.z*wv[1].z + q1.w*wv[1].w;
                acc += q2.x*wv[2].x + q2.y*wv[2].y + q2.z*wv[2].z + q2.w*wv[2].w;
                acc += q3.x*wv[3].x + q3.y*wv[3].y + q3.z*wv[3].z + q3.w*wv[3].w;
                acc += q4.x*wv[4].x + q4.y*wv[4].y + q4.z*wv[4].z + q4.w*wv[4].w;
                acc += q5.x*wv[5].x + q5.y*wv[5].y + q5.z*wv[5].z + q5.w*wv[5].w;
                acc += q6.x*wv[6].x + q6.y*wv[6].y + q6.z*wv[6].z + q6.w*wv[6].w;
                acc += q7.x*wv[7].x + q7.y*wv[7].y + q7.z*wv[7].z + q7.w*wv[7].w;
                acc += __shfl_down(acc, 8, 16);
                acc += __shfl_down(acc, 4, 16);
                acc += __shfl_down(acc, 2, 16);
                acc += __shfl_down(acc, 1, 16);
                if (fl == 0)
                    out[(size_t)(nb0 + bl) * (TT * DD) + (s - (TP1 + 1)) * DD + d] =
                        1.0f / (1.0f + __expf(-(acc + fc_b[d])));
            }
        }

        // ---- hrow (fp32, for fc) ----
        {
            float* hrp = (float*)(wsb + HROW_B + (unsigned)(((par^1))*8 + cl)*131072u);
            const int kl = tid & 15, nl0 = tid >> 4;
#pragma unroll
            for (int i = 0; i < 2; ++i) {
                const int nl = nl0 + i * 32;
                hrp[nl * 512 + j0 + kl] = smem[L_HNEW + kl * 64 + nl];
            }
        }
        // ---- pack h -> bf16 hi/lo fragments for next step's GEMM ----
        if (tid < 256) {
            const int col = tid & 63, jblk = (tid >> 6) & 1, arr = (tid >> 7) & 1;
            const int jb = wl * 2 + jblk;          // global 8-row block
            const int kt = jb >> 2, gg = jb & 3;
            s8v v;
#pragma unroll
            for (int i = 0; i < 8; ++i) {
                float f = smem[L_HNEW + (jblk * 8 + i) * 64 + col];
                unsigned short hi = bf16hi_rne(f);
                unsigned short w = hi;
                if (arr) {
                    float fh = __uint_as_float(((unsigned)hi) << 16);
                    w = bf16hi_rne(f - fh);
                }
                v[i] = (short)w;
            }
            char* dst = wsb + HFRAG_B + (unsigned)(((par^1))*8 + cl)*131072u
                        + (unsigned)(kt*8192 + ((arr*4 + gg)*64 + col)*16);
            *(s8v*)dst = v;
        }
        asm volatile("s_waitcnt vmcnt(0)" ::: "memory");
        __syncthreads();

        // ---- signal ----
        if (tid == 0) {
            if (fast) {
                __hip_atomic_store(flg + wl, (unsigned)(s + 1),
                                   __ATOMIC_RELAXED, __HIP_MEMORY_SCOPE_AGENT);
            } else {
                __builtin_amdgcn_fence(__ATOMIC_RELEASE, "agent");
                __hip_atomic_store(flg + wl, (unsigned)(s + 1),
                                   __ATOMIC_RELEASE, __HIP_MEMORY_SCOPE_AGENT);
            }
        }
    }

    // ---- tail fc: td = 255 from h(513) ----
    {
        if (tid < WPC) {
            for (;;) {
                unsigned v = __hip_atomic_load(flags + cl * WPC + tid,
                                               __ATOMIC_RELAXED, __HIP_MEMORY_SCOPE_AGENT);
                if (__all((int)(v >= (unsigned)NSTEP))) break;
                __builtin_amdgcn_s_sleep(1);
            }
        }
        __syncthreads();
        if (fast) __builtin_amdgcn_fence(__ATOMIC_ACQUIRE, "workgroup");
        else      __builtin_amdgcn_fence(__ATOMIC_ACQUIRE, "agent");

        const int fg = tid >> 4, fl = tid & 15;
        if (fg < 2 * DD) {
            const int bsel = fg / DD, d = fg - bsel * DD;
            const int bl = wl * 2 + bsel;
            const char* hp = wsb + HROW_B + (unsigned)((NSTEP & 1)*8 + cl)*131072u
                             + (unsigned)(bl*512 + fl*32)*4u;
            f4v q0,q1,q2,q3,q4,q5,q6,q7;
            ld16f(q0, hp);      ld16f(q1, hp+16);  ld16f(q2, hp+32);  ld16f(q3, hp+48);
            ld16f(q4, hp+64);   ld16f(q5, hp+80);  ld16f(q6, hp+96);  ld16f(q7, hp+112);
            const f4v* wv = (const f4v*)(fc_W + d * HH + fl * 32);
            wait_vm0_8f(q0,q1,q2,q3,q4,q5,q6,q7);
            float acc = 0.f;
            acc += q0.x*wv[0].x + q0.y*wv[0].y + q0.z*wv[0].z + q0.w*wv[0].w;
            acc += q1.x*wv[1].x + q1.y*wv[1].y + q1.z*wv[1].z + q1.w*wv[1].w;
            acc += q2.x*wv[2].x + q2.y*wv[2].y + q2.z*wv[2].z + q2.w*wv[2].w;
            acc += q3.x*wv[3].x + q3.y*wv[3].y + q3.z*wv[3].z + q3.w*wv[3].w;
            acc += q4.x*wv[4].x + q4.y*wv[4].y + q4.z*wv[4].z + q4.w*wv[4].w;
            acc += q5.x*wv[5].x + q5.y*wv[5].y + q5.z*wv[5].z + q5.w*wv[5].w;
            acc += q6.x*wv[6].x + q6.y*wv[6].y + q6.z*wv[6].z + q6.w*wv[6].w;
            acc += q7.x*wv[7].x + q7.y*wv[7].y + q7.z*wv[7].z + q7.w*wv[7].w;
            acc += __shfl_down(acc, 8, 16);
            acc += __shfl_down(acc, 4, 16);
            acc += __shfl_down(acc, 2, 16);
            acc += __shfl_down(acc, 1, 16);
            if (fl == 0)
                out[(size_t)(nb0 + bl) * (TT * DD) + 255 * DD + d] =
                    1.0f / (1.0f + __expf(-(acc + fc_b[d])));
        }
    }
}

extern "C" void kernel_launch(void* const* d_in, const int* in_sizes, int n_in,
                              void* d_out, int out_size, void* d_ws, size_t ws_size,
                              hipStream_t stream) {
    (void)in_sizes; (void)n_in; (void)out_size; (void)ws_size;
    const float* x    = (const float*)d_in[0];
    const float* W_ih = (const float*)d_in[1];
    const float* W_hh = (const float*)d_in[2];
    const float* b_ih = (const float*)d_in[3];
    const float* b_hh = (const float*)d_in[4];
    const float* fc_W = (const float*)d_in[5];
    const float* fc_b = (const float*)d_in[6];
    const float* h0   = (const float*)d_in[7];
    const float* c0   = (const float*)d_in[8];
    float* out = (float*)d_out;
    char*  wsb = (char*)d_ws;

    hipLaunchKernelGGL(rnn_init_kernel, dim3(4096), dim3(256), 0, stream,
                       W_hh, h0, wsb);
    hipLaunchKernelGGL(rnn_persist_kernel, dim3(NWG), dim3(THREADS), 0, stream,
                       x, W_ih, b_ih, b_hh, fc_W, fc_b, c0, wsb, out);
}

// Round 8
// 5678.631 us; speedup vs baseline: 4.8283x; 1.0611x over previous
//
#include <hip/hip_runtime.h>

// N=512 batch, T=256, H=512, D=9. 257 encode + 256 decode steps, LSTM + fc(sigmoid).
// Persistent kernel, 16 clusters x 32 wgs x 256 threads (2 wgs/CU for latency overlap).
// Cluster owns 32 batch; wg owns 16 hidden units. GEMM via mfma_f32_16x16x32_bf16 with
// bf16 hi/lo split (3-term). W_hh fragments register-resident. h exchanged via XCD-local
// L2 (sc0 loads, relaxed flags); agent-fence fallback if cluster spans XCDs.

#define TT 256
#define HH 512
#define DD 9
#define TP1 257
#define NSTEP 513
#define THREADS 256
#define NWG 512
#define NCL 16
#define WPC 32
#define GSTR 34

// ws byte offsets
#define WF_HI_B 0u          // Wfrag hi: [wl32][rb4][kt16][lane64][i8] bf16 = 2 MB
#define WF_LO_B 2097152u    // Wfrag lo: 2 MB
#define HFRAG_B 4194304u    // hfrag: [par2][cl16] x 65536 B ([kt16][arr2][g4][col32][i8] bf16)
#define HROW_B  6291456u    // hrow:  [par2][cl16] x 65536 B ([col32][k512] f32)
#define U32_B   8388608u    // flags[512] @0 | ctr @768 | xcc[512] @1024

// LDS float offsets (8004 floats = 31.3 KB)
#define L_CH    0           // chunk bufs: 2 dbuf x 8192 B = 4096 floats
#define L_GATES 4096        // gates[64][GSTR]
#define L_C     6272        // c[u16][b32]
#define L_BIAS  6784
#define L_WIH   6848        // wih[64][10]
#define L_HNEW  7488        // hnew[u16][b32]
#define L_MISC  8000
#define L_TOT   8004

typedef short s8v __attribute__((ext_vector_type(8)));
typedef float f4v __attribute__((ext_vector_type(4)));
typedef int   i4v __attribute__((ext_vector_type(4)));

__device__ __forceinline__ float sigmoidf_(float v){ return 1.0f/(1.0f+__expf(-v)); }
__device__ __forceinline__ float tanhf_(float v){ return 1.0f - 2.0f/(__expf(2.0f*v)+1.0f); }
__device__ __forceinline__ unsigned short bf16hi_rne(float f){
    unsigned u = __float_as_uint(f);
    return (unsigned short)((u + 0x7fffu + ((u>>16)&1u)) >> 16);
}

__device__ __forceinline__ void ld16i(i4v& d, const char* p){
    asm volatile("global_load_dwordx4 %0, %1, off sc0" : "=v"(d) : "v"(p));
}
__device__ __forceinline__ void ld16f(f4v& d, const char* p){
    asm volatile("global_load_dwordx4 %0, %1, off sc0" : "=v"(d) : "v"(p));
}
__device__ __forceinline__ void wait_vm2_i(i4v& a, i4v& b){
    asm volatile("s_waitcnt vmcnt(2)" : "+v"(a), "+v"(b) :: "memory");
}
__device__ __forceinline__ void wait_vm0_i(i4v& a, i4v& b){
    asm volatile("s_waitcnt vmcnt(0)" : "+v"(a), "+v"(b) :: "memory");
}
__device__ __forceinline__ void wait_vm0_8i(i4v& a0,i4v& a1,i4v& a2,i4v& a3,
                                            i4v& a4,i4v& a5,i4v& a6,i4v& a7){
    asm volatile("s_waitcnt vmcnt(0)"
                 : "+v"(a0),"+v"(a1),"+v"(a2),"+v"(a3),
                   "+v"(a4),"+v"(a5),"+v"(a6),"+v"(a7) :: "memory");
}
__device__ __forceinline__ void wait_vm0_8f(f4v& a0,f4v& a1,f4v& a2,f4v& a3,
                                            f4v& a4,f4v& a5,f4v& a6,f4v& a7){
    asm volatile("s_waitcnt vmcnt(0)"
                 : "+v"(a0),"+v"(a1),"+v"(a2),"+v"(a3),
                   "+v"(a4),"+v"(a5),"+v"(a6),"+v"(a7) :: "memory");
}

// init: W_hh -> A-fragments (hi/lo); h0 -> hfrag[par=0]; zero flags/ctr/xcc.
__global__ void rnn_init_kernel(const float* __restrict__ W_hh,
                                const float* __restrict__ h0,
                                char* __restrict__ wsb) {
    int idx = blockIdx.x * blockDim.x + threadIdx.x;   // 0 .. 1048575
    {
        int i  = idx & 7;
        int l  = (idx >> 3) & 63;
        int kt = (idx >> 9) & 15;
        int rb = (idx >> 13) & 3;
        int wl = idx >> 15;
        int m = l & 15, g = l >> 4;
        int grow = rb * 512 + wl * 16 + m;
        int k = kt * 32 + g * 8 + i;
        float v = W_hh[grow * 512 + k];
        unsigned short hi = bf16hi_rne(v);
        float fh = __uint_as_float(((unsigned)hi) << 16);
        unsigned short lo = bf16hi_rne(v - fh);
        ((unsigned short*)(wsb + WF_HI_B))[idx] = hi;
        ((unsigned short*)(wsb + WF_LO_B))[idx] = lo;
    }
    if (idx < 524288) {   // hfrag par 0: [cl16][kt16][arr2][g4][col32][i8]
        int i   = idx & 7;
        int g   = (idx >> 8) & 3;
        int arr = (idx >> 10) & 1;
        int kt  = (idx >> 11) & 15;
        int cl  = idx >> 15;
        int rem = idx & 32767;
        int j = kt * 32 + g * 8 + i;
        float v = h0[j];
        unsigned short hi = bf16hi_rne(v);
        unsigned short w = hi;
        if (arr) {
            float fh = __uint_as_float(((unsigned)hi) << 16);
            w = bf16hi_rne(v - fh);
        }
        ((unsigned short*)(wsb + HFRAG_B + (unsigned)cl * 65536u))[rem] = w;
    }
    if (idx < 2048) ((unsigned int*)(wsb + U32_B))[idx] = 0u;
}

__global__ __launch_bounds__(THREADS, 2)
void rnn_persist_kernel(const float* __restrict__ x,
                        const float* __restrict__ W_ih,
                        const float* __restrict__ b_ih,
                        const float* __restrict__ b_hh,
                        const float* __restrict__ fc_W,
                        const float* __restrict__ fc_b,
                        const float* __restrict__ c0,
                        char* __restrict__ wsb,
                        float* __restrict__ out) {
    __shared__ float smem[L_TOT];
    char* ldsch = (char*)smem;          // chunk bufs at byte 0

    const int wg  = blockIdx.x;
    const int cl  = wg & 15;            // cluster -> XCD cl&7 under round-robin
    const int wl  = wg >> 4;            // 0..31
    const int j0  = wl * 16;
    const int nb0 = cl * 32;
    const int tid = threadIdx.x;
    const int lane = tid & 63;
    const int rb   = tid >> 6;          // wave id = row-tile (gate)
    const int m    = lane & 15;
    const int g    = lane >> 4;

    unsigned int* flags = (unsigned int*)(wsb + U32_B);        // [cl*32 + wl]
    unsigned int* ctr   = (unsigned int*)(wsb + U32_B + 3072);
    unsigned int* xccb  = (unsigned int*)(wsb + U32_B + 4096); // [wg]

    // ---- one-time: constants to LDS ----
    {
        int u = tid >> 5, b = tid & 31;
        smem[L_C + u * 32 + b]       = c0[j0 + u];
        smem[L_C + (u + 8) * 32 + b] = c0[j0 + 8 + u];
        if (tid < 64) {
            int gt = tid >> 4, u2 = tid & 15;
            smem[L_BIAS + tid] = b_ih[gt*512 + wl*16 + u2] + b_hh[gt*512 + wl*16 + u2];
        }
        for (int i = tid; i < 64 * DD; i += THREADS) {
            int r = i / DD, d = i - r * DD;
            int gt = r >> 4, u2 = r & 15;
            smem[L_WIH + r * 10 + d] = W_ih[(gt*512 + wl*16 + u2) * DD + d];
        }
    }

    // ---- one-time: W A-fragments into registers (hi + lo) ----
    s8v wAh[16], wAl[16];
    {
        const char* base = wsb + (unsigned)(((wl*4 + rb)*16)*64 + lane)*16u;
#pragma unroll
        for (int kt = 0; kt < 16; ++kt) {
            wAh[kt] = *(const s8v*)(base + WF_HI_B + kt*1024);
            wAl[kt] = *(const s8v*)(base + WF_LO_B + kt*1024);
        }
    }

    // ---- startup: publish XCD id, grid barrier, co-location check ----
    if (tid == 0) {
        unsigned xcc;
        asm volatile("s_getreg_b32 %0, hwreg(HW_REG_XCC_ID, 0, 32)" : "=s"(xcc));
        __hip_atomic_store(xccb + wg, xcc + 1u, __ATOMIC_RELAXED, __HIP_MEMORY_SCOPE_AGENT);
        __hip_atomic_fetch_add(ctr, 1u, __ATOMIC_RELEASE, __HIP_MEMORY_SCOPE_AGENT);
        while (__hip_atomic_load(ctr, __ATOMIC_RELAXED, __HIP_MEMORY_SCOPE_AGENT) < NWG)
            __builtin_amdgcn_s_sleep(8);
    }
    __syncthreads();
    {
        unsigned v = (tid < WPC)
            ? __hip_atomic_load(xccb + tid * NCL + cl, __ATOMIC_RELAXED,
                                __HIP_MEMORY_SCOPE_AGENT) : 0u;
        unsigned v0 = __shfl(v, 0, 64);
        bool ok = (tid >= WPC) || (v != 0u && v == v0);
        unsigned long long mk = __ballot(ok);
        if (tid == 0) smem[L_MISC] = (mk == ~0ull) ? 1.0f : 0.0f;
    }
    __syncthreads();
    const bool fast = (smem[L_MISC] != 0.0f);

    const int cw = tid >> 5;           // cell: units {cw, cw+8}
    const int cb = tid & 31;           // cell: batch

    for (int s = 0; s < NSTEP; ++s) {
        const int par = s & 1;
        const char* hsrc = wsb + HFRAG_B + (unsigned)(par*16 + cl) * 65536u;
        unsigned int* flg = flags + cl * 32;

        // ---- step-start: one-shot all-32 flag check ----
        bool allready = true;
        if (s > 0) {
            if (fast) {
                const char* fb = (const char*)flg;
                i4v a0,a1,a2,a3,a4,a5,a6,a7;
                ld16i(a0, fb);      ld16i(a1, fb+16);  ld16i(a2, fb+32);  ld16i(a3, fb+48);
                ld16i(a4, fb+64);   ld16i(a5, fb+80);  ld16i(a6, fb+96);  ld16i(a7, fb+112);
                wait_vm0_8i(a0,a1,a2,a3,a4,a5,a6,a7);
                unsigned mn = 0xffffffffu;
#define MN4(A) mn = min(mn,(unsigned)A.x); mn = min(mn,(unsigned)A.y); \
               mn = min(mn,(unsigned)A.z); mn = min(mn,(unsigned)A.w);
                MN4(a0) MN4(a1) MN4(a2) MN4(a3) MN4(a4) MN4(a5) MN4(a6) MN4(a7)
#undef MN4
                allready = (mn >= (unsigned)s);
            } else {
                allready = false;
            }
        }
        __builtin_amdgcn_fence(__ATOMIC_ACQUIRE, "workgroup");

        // ---- x prefetch (encode) ----
        float xv[DD];
        if (s < TP1) {
            const float* xp = x + (size_t)(nb0 + cb) * (TP1 * DD) + s * DD;
#pragma unroll
            for (int d = 0; d < DD; ++d) xv[d] = xp[d];
        }

        // ---- GEMM: 8 chunks (2 kt each), per-thread producer polls, MFMA ----
        f4v acc0 = {0.f,0.f,0.f,0.f}, acc1 = {0.f,0.f,0.f,0.f};
        {
            i4v cur0, cur1, nxt0, nxt1;
            if (s > 0 && !allready) {
                volatile unsigned int* f0 = flg + 0 + (g >> 1);
                volatile unsigned int* f1 = f0 + 2;
                while (__hip_atomic_load((unsigned int*)f0, __ATOMIC_RELAXED, __HIP_MEMORY_SCOPE_AGENT) < (unsigned)s ||
                       __hip_atomic_load((unsigned int*)f1, __ATOMIC_RELAXED, __HIP_MEMORY_SCOPE_AGENT) < (unsigned)s)
                    __builtin_amdgcn_s_sleep(1);
                if (!fast) __builtin_amdgcn_fence(__ATOMIC_ACQUIRE, "agent");
            }
            ld16i(cur0, hsrc + tid*16);
            ld16i(cur1, hsrc + 4096 + tid*16);
#pragma unroll
            for (int c = 0; c < 8; ++c) {
                if (c < 7) {
                    if (s > 0 && !allready) {
                        volatile unsigned int* f0 = flg + 4*(c+1) + (g >> 1);
                        volatile unsigned int* f1 = f0 + 2;
                        while (__hip_atomic_load((unsigned int*)f0, __ATOMIC_RELAXED, __HIP_MEMORY_SCOPE_AGENT) < (unsigned)s ||
                               __hip_atomic_load((unsigned int*)f1, __ATOMIC_RELAXED, __HIP_MEMORY_SCOPE_AGENT) < (unsigned)s)
                            __builtin_amdgcn_s_sleep(1);
                        if (!fast) __builtin_amdgcn_fence(__ATOMIC_ACQUIRE, "agent");
                    }
                    ld16i(nxt0, hsrc + (c+1)*8192 + tid*16);
                    ld16i(nxt1, hsrc + (c+1)*8192 + 4096 + tid*16);
                    wait_vm2_i(cur0, cur1);
                } else {
                    wait_vm0_i(cur0, cur1);
                }
                *(i4v*)(ldsch + (c&1)*8192 + tid*16) = cur0;
                *(i4v*)(ldsch + (c&1)*8192 + 4096 + tid*16) = cur1;
                asm volatile("s_waitcnt lgkmcnt(0)" ::: "memory");
                __builtin_amdgcn_s_barrier();
#pragma unroll
                for (int j = 0; j < 2; ++j) {
                    const int kt = 2*c + j;
                    const char* bb = ldsch + (c&1)*8192 + j*4096;
                    s8v bh0 = *(const s8v*)(bb + g*512        + m*16);
                    s8v bh1 = *(const s8v*)(bb + g*512        + m*16 + 256);
                    s8v bl0 = *(const s8v*)(bb + 2048 + g*512 + m*16);
                    s8v bl1 = *(const s8v*)(bb + 2048 + g*512 + m*16 + 256);
                    acc0 = __builtin_amdgcn_mfma_f32_16x16x32_bf16(wAh[kt], bh0, acc0, 0,0,0);
                    acc1 = __builtin_amdgcn_mfma_f32_16x16x32_bf16(wAh[kt], bh1, acc1, 0,0,0);
                    acc0 = __builtin_amdgcn_mfma_f32_16x16x32_bf16(wAl[kt], bh0, acc0, 0,0,0);
                    acc1 = __builtin_amdgcn_mfma_f32_16x16x32_bf16(wAl[kt], bh1, acc1, 0,0,0);
                    acc0 = __builtin_amdgcn_mfma_f32_16x16x32_bf16(wAh[kt], bl0, acc0, 0,0,0);
                    acc1 = __builtin_amdgcn_mfma_f32_16x16x32_bf16(wAh[kt], bl1, acc1, 0,0,0);
                }
                cur0 = nxt0; cur1 = nxt1;
            }
        }

        // ---- acc -> gates LDS (C/D: row = g*4 + reg, col = m) ----
        {
            float* gp = smem + L_GATES + (rb*16 + g*4) * GSTR + m;
            gp[0*GSTR]      = acc0.x; gp[1*GSTR]      = acc0.y;
            gp[2*GSTR]      = acc0.z; gp[3*GSTR]      = acc0.w;
            gp[0*GSTR + 16] = acc1.x; gp[1*GSTR + 16] = acc1.y;
            gp[2*GSTR + 16] = acc1.z; gp[3*GSTR + 16] = acc1.w;
        }
        asm volatile("s_waitcnt lgkmcnt(0)" ::: "memory");
        __builtin_amdgcn_s_barrier();

        // ---- LSTM cell: units {cw, cw+8}, batch cb ----
        {
#pragma unroll
            for (int half = 0; half < 2; ++half) {
                const int u = cw + half * 8;
                float vi = smem[L_GATES + (u) * GSTR + cb]      + smem[L_BIAS + u];
                float vf = smem[L_GATES + (16 + u) * GSTR + cb] + smem[L_BIAS + 16 + u];
                float vg = smem[L_GATES + (32 + u) * GSTR + cb] + smem[L_BIAS + 32 + u];
                float vo = smem[L_GATES + (48 + u) * GSTR + cb] + smem[L_BIAS + 48 + u];
                if (s < TP1) {
                    float di = 0.f, df = 0.f, dg = 0.f, dq = 0.f;
#pragma unroll
                    for (int d = 0; d < DD; ++d) {
                        di += xv[d] * smem[L_WIH + (u) * 10 + d];
                        df += xv[d] * smem[L_WIH + (16 + u) * 10 + d];
                        dg += xv[d] * smem[L_WIH + (32 + u) * 10 + d];
                        dq += xv[d] * smem[L_WIH + (48 + u) * 10 + d];
                    }
                    vi += di; vf += df; vg += dg; vo += dq;
                }
                float c_old = smem[L_C + u * 32 + cb];
                float si = sigmoidf_(vi), sf = sigmoidf_(vf), so = sigmoidf_(vo);
                float tg = tanhf_(vg);
                float cn = sf * c_old + si * tg;
                smem[L_C + u * 32 + cb] = cn;
                smem[L_HNEW + u * 32 + cb] = so * tanhf_(cn);
            }
        }
        asm volatile("s_waitcnt lgkmcnt(0)" ::: "memory");
        __builtin_amdgcn_s_barrier();

        // ---- fc output for h(s) (decode): out[:, s-258, :] ----
        if (s >= TP1 + 1) {
            const int fg = tid >> 4, fl = tid & 15;
            if (fg < DD) {
                const char* hp = wsb + HROW_B + (unsigned)(par*16 + cl)*65536u
                                 + (unsigned)(wl*512 + fl*32)*4u;
                f4v q0,q1,q2,q3,q4,q5,q6,q7;
                ld16f(q0, hp);      ld16f(q1, hp+16);  ld16f(q2, hp+32);  ld16f(q3, hp+48);
                ld16f(q4, hp+64);   ld16f(q5, hp+80);  ld16f(q6, hp+96);  ld16f(q7, hp+112);
                const f4v* wv = (const f4v*)(fc_W + fg * HH + fl * 32);
                wait_vm0_8f(q0,q1,q2,q3,q4,q5,q6,q7);
                float acc = 0.f;
                acc += q0.x*wv[0].x + q0.y*wv[0].y + q0.z*wv[0].z + q0.w*wv[0].w;
                acc += q1.x*wv[1].x + q1.y*wv[1].y + q1.z*wv[1].z + q1.w*wv[1].w;
                acc += q2.x*wv[2].x + q2.y*wv[2].y + q2.z*wv[2].z + q2.w*wv[2].w;
                acc += q3.x*wv[3].x + q3.y*wv[3].y + q3.z*wv[3].z + q3.w*wv[3].w;
                acc += q4.x*wv[4].x + q4.y*wv[4].y + q4.z*wv[4].z + q4.w*wv[4].w;
                acc += q5.x*wv[5].x + q5.y*wv[5].y + q5.z*wv[5].z + q5.w*wv[5].w;
                acc += q6.x*wv[6].x + q6.y*wv[6].y + q6.z*wv[6].z + q6.w*wv[6].w;
                acc += q7.x*wv[7].x + q7.y*wv[7].y + q7.z*wv[7].z + q7.w*wv[7].w;
                acc += __shfl_down(acc, 8, 16);
                acc += __shfl_down(acc, 4, 16);
                acc += __shfl_down(acc, 2, 16);
                acc += __shfl_down(acc, 1, 16);
                if (fl == 0)
                    out[(size_t)(nb0 + wl) * (TT * DD) + (s - (TP1 + 1)) * DD + fg] =
                        1.0f / (1.0f + __expf(-(acc + fc_b[fg])));
            }
        }

        // ---- hrow (fp32, for fc): cols 0..31, k rows j0..j0+15 ----
        {
            float* hrp = (float*)(wsb + HROW_B + (unsigned)((par^1)*16 + cl)*65536u);
            const int kl = tid & 15, nl0 = tid >> 4;
#pragma unroll
            for (int i = 0; i < 2; ++i) {
                const int nl = nl0 + i * 16;
                hrp[nl * 512 + j0 + kl] = smem[L_HNEW + kl * 32 + nl];
            }
        }
        // ---- pack h -> bf16 hi/lo fragments for next step ----
        if (tid < 128) {
            const int col = tid & 31, jblk = (tid >> 5) & 1, arr = (tid >> 6) & 1;
            const int jb = wl * 2 + jblk;
            const int kt = jb >> 2, gg = jb & 3;
            s8v v;
#pragma unroll
            for (int i = 0; i < 8; ++i) {
                float f = smem[L_HNEW + (jblk * 8 + i) * 32 + col];
                unsigned short hi = bf16hi_rne(f);
                unsigned short w = hi;
                if (arr) {
                    float fh = __uint_as_float(((unsigned)hi) << 16);
                    w = bf16hi_rne(f - fh);
                }
                v[i] = (short)w;
            }
            char* dst = wsb + HFRAG_B + (unsigned)((par^1)*16 + cl)*65536u
                        + (unsigned)(kt*4096 + arr*2048 + gg*512 + col*16);
            *(s8v*)dst = v;
        }
        asm volatile("s_waitcnt vmcnt(0)" ::: "memory");
        __syncthreads();

        // ---- signal ----
        if (tid == 0) {
            if (fast) {
                __hip_atomic_store(flg + wl, (unsigned)(s + 1),
                                   __ATOMIC_RELAXED, __HIP_MEMORY_SCOPE_AGENT);
            } else {
                __builtin_amdgcn_fence(__ATOMIC_RELEASE, "agent");
                __hip_atomic_store(flg + wl, (unsigned)(s + 1),
                                   __ATOMIC_RELEASE, __HIP_MEMORY_SCOPE_AGENT);
            }
        }
    }

    // ---- tail fc: td = 255 from h(513) ----
    {
        if (tid < WPC) {
            for (;;) {
                unsigned v = __hip_atomic_load(flags + cl * 32 + tid,
                                               __ATOMIC_RELAXED, __HIP_MEMORY_SCOPE_AGENT);
                if (__all((int)(v >= (unsigned)NSTEP))) break;
                __builtin_amdgcn_s_sleep(1);
            }
        }
        __syncthreads();
        if (fast) __builtin_amdgcn_fence(__ATOMIC_ACQUIRE, "workgroup");
        else      __builtin_amdgcn_fence(__ATOMIC_ACQUIRE, "agent");

        const int fg = tid >> 4, fl = tid & 15;
        if (fg < DD) {
            const char* hp = wsb + HROW_B + (unsigned)((NSTEP & 1)*16 + cl)*65536u
                             + (unsigned)(wl*512 + fl*32)*4u;
            f4v q0,q1,q2,q3,q4,q5,q6,q7;
            ld16f(q0, hp);      ld16f(q1, hp+16);  ld16f(q2, hp+32);  ld16f(q3, hp+48);
            ld16f(q4, hp+64);   ld16f(q5, hp+80);  ld16f(q6, hp+96);  ld16f(q7, hp+112);
            const f4v* wv = (const f4v*)(fc_W + fg * HH + fl * 32);
            wait_vm0_8f(q0,q1,q2,q3,q4,q5,q6,q7);
            float acc = 0.f;
            acc += q0.x*wv[0].x + q0.y*wv[0].y + q0.z*wv[0].z + q0.w*wv[0].w;
            acc += q1.x*wv[1].x + q1.y*wv[1].y + q1.z*wv[1].z + q1.w*wv[1].w;
            acc += q2.x*wv[2].x + q2.y*wv[2].y + q2.z*wv[2].z + q2.w*wv[2].w;
            acc += q3.x*wv[3].x + q3.y*wv[3].y + q3.z*wv[3].z + q3.w*wv[3].w;
            acc += q4.x*wv[4].x + q4.y*wv[4].y + q4.z*wv[4].z + q4.w*wv[4].w;
            acc += q5.x*wv[5].x + q5.y*wv[5].y + q5.z*wv[5].z + q5.w*wv[5].w;
            acc += q6.x*wv[6].x + q6.y*wv[6].y + q6.z*wv[6].z + q6.w*wv[6].w;
            acc += q7.x*wv[7].x + q7.y*wv[7].y + q7.z*wv[7].z + q7.w*wv[7].w;
            acc += __shfl_down(acc, 8, 16);
            acc += __shfl_down(acc, 4, 16);
            acc += __shfl_down(acc, 2, 16);
            acc += __shfl_down(acc, 1, 16);
            if (fl == 0)
                out[(size_t)(nb0 + wl) * (TT * DD) + 255 * DD + fg] =
                    1.0f / (1.0f + __expf(-(acc + fc_b[fg])));
        }
    }
}

extern "C" void kernel_launch(void* const* d_in, const int* in_sizes, int n_in,
                              void* d_out, int out_size, void* d_ws, size_t ws_size,
                              hipStream_t stream) {
    (void)in_sizes; (void)n_in; (void)out_size; (void)ws_size;
    const float* x    = (const float*)d_in[0];
    const float* W_ih = (const float*)d_in[1];
    const float* W_hh = (const float*)d_in[2];
    const float* b_ih = (const float*)d_in[3];
    const float* b_hh = (const float*)d_in[4];
    const float* fc_W = (const float*)d_in[5];
    const float* fc_b = (const float*)d_in[6];
    const float* h0   = (const float*)d_in[7];
    const float* c0   = (const float*)d_in[8];
    float* out = (float*)d_out;
    char*  wsb = (char*)d_ws;

    hipLaunchKernelGGL(rnn_init_kernel, dim3(4096), dim3(256), 0, stream,
                       W_hh, h0, wsb);
    hipLaunchKernelGGL(rnn_persist_kernel, dim3(NWG), dim3(THREADS), 0, stream,
                       x, W_ih, b_ih, b_hh, fc_W, fc_b, c0, wsb, out);
}

// Round 10
// 4428.614 us; speedup vs baseline: 6.1912x; 1.2823x over previous
//
#include <hip/hip_runtime.h>

// N=512 batch, T=256, H=512, D=9. 257 encode + 256 decode steps, LSTM + fc(sigmoid).
// Persistent kernel, 16 clusters x 32 wgs x 256 threads (2 wgs/CU). Cluster owns 32 batch;
// wg owns 16 hidden units. GEMM via mfma_f32_16x16x32_bf16, bf16 hi/lo 3-term split.
// W_hh fragments register-resident. h exchanged via XCD-local L2 (sc0 loads for DATA only).
// R10: R9 schedule (whole-step preload, 1 vm-stall, 2-phase staging) with the step-wait
// poll done via __hip_atomic_load per lane (coherence-point read) — raw sc0 flag polls
// livelocked R9 because agent atomic stores bypass the local L2 that sc0 loads read.

#define TT 256
#define HH 512
#define DD 9
#define TP1 257
#define NSTEP 513
#define THREADS 256
#define NWG 512
#define NCL 16
#define WPC 32
#define GSTR 34

// ws byte offsets
#define WF_HI_B 0u          // Wfrag hi: [wl32][rb4][kt16][lane64][i8] bf16 = 2 MB
#define WF_LO_B 2097152u    // Wfrag lo: 2 MB
#define HFRAG_B 4194304u    // hfrag: [par2][cl16] x 65536 B ([kt16][arr2][g4][col32][i8] bf16)
#define HROW_B  6291456u    // hrow:  [par2][cl16] x 65536 B ([col32][k512] f32)
#define U32_B   8388608u    // flags[512] | ctr @+3072 | xcc @+4096

// LDS float offsets (12100 floats = 47.3 KB)
#define L_ST    0           // staging: 8 kt x 4096 B = 8192 floats (reused A/B phase)
#define L_GATES 8192        // gates[64][GSTR]
#define L_C     10368       // c[u16][b32]
#define L_BIAS  10880
#define L_WIH   10944       // wih[64][10]
#define L_HNEW  11584       // hnew[u16][b32]
#define L_MISC  12096
#define L_TOT   12100

typedef short s8v __attribute__((ext_vector_type(8)));
typedef float f4v __attribute__((ext_vector_type(4)));
typedef int   i4v __attribute__((ext_vector_type(4)));

__device__ __forceinline__ float sigmoidf_(float v){ return 1.0f/(1.0f+__expf(-v)); }
__device__ __forceinline__ float tanhf_(float v){ return 1.0f - 2.0f/(__expf(2.0f*v)+1.0f); }
__device__ __forceinline__ unsigned short bf16hi_rne(float f){
    unsigned u = __float_as_uint(f);
    return (unsigned short)((u + 0x7fffu + ((u>>16)&1u)) >> 16);
}

__device__ __forceinline__ void ld16i(i4v& d, const char* p){
    asm volatile("global_load_dwordx4 %0, %1, off sc0" : "=v"(d) : "v"(p));
}
__device__ __forceinline__ void ld16f(f4v& d, const char* p){
    asm volatile("global_load_dwordx4 %0, %1, off sc0" : "=v"(d) : "v"(p));
}
__device__ __forceinline__ void wait_vm0_mem(){
    asm volatile("s_waitcnt vmcnt(0)" ::: "memory");
}
__device__ __forceinline__ void wait_vm0_8f(f4v& a0,f4v& a1,f4v& a2,f4v& a3,
                                            f4v& a4,f4v& a5,f4v& a6,f4v& a7){
    asm volatile("s_waitcnt vmcnt(0)"
                 : "+v"(a0),"+v"(a1),"+v"(a2),"+v"(a3),
                   "+v"(a4),"+v"(a5),"+v"(a6),"+v"(a7) :: "memory");
}
__device__ __forceinline__ void lgkm0_bar(){
    asm volatile("s_waitcnt lgkmcnt(0)" ::: "memory");
    __builtin_amdgcn_s_barrier();
}

// init: W_hh -> A-fragments (hi/lo); h0 -> hfrag[par=0]; zero flags/ctr/xcc.
__global__ void rnn_init_kernel(const float* __restrict__ W_hh,
                                const float* __restrict__ h0,
                                char* __restrict__ wsb) {
    int idx = blockIdx.x * blockDim.x + threadIdx.x;   // 0 .. 1048575
    {
        int i  = idx & 7;
        int l  = (idx >> 3) & 63;
        int kt = (idx >> 9) & 15;
        int rb = (idx >> 13) & 3;
        int wl = idx >> 15;
        int m = l & 15, g = l >> 4;
        int grow = rb * 512 + wl * 16 + m;
        int k = kt * 32 + g * 8 + i;
        float v = W_hh[grow * 512 + k];
        unsigned short hi = bf16hi_rne(v);
        float fh = __uint_as_float(((unsigned)hi) << 16);
        unsigned short lo = bf16hi_rne(v - fh);
        ((unsigned short*)(wsb + WF_HI_B))[idx] = hi;
        ((unsigned short*)(wsb + WF_LO_B))[idx] = lo;
    }
    if (idx < 524288) {   // hfrag par 0: [cl16][kt16][arr2][g4][col32][i8]
        int i   = idx & 7;
        int arr = (idx >> 10) & 1;
        int kt  = (idx >> 11) & 15;
        int cl  = idx >> 15;
        int rem = idx & 32767;
        int j = kt * 32 + ((idx >> 8) & 3) * 8 + i;
        float v = h0[j];
        unsigned short hi = bf16hi_rne(v);
        unsigned short w = hi;
        if (arr) {
            float fh = __uint_as_float(((unsigned)hi) << 16);
            w = bf16hi_rne(v - fh);
        }
        ((unsigned short*)(wsb + HFRAG_B + (unsigned)cl * 65536u))[rem] = w;
    }
    if (idx < 2048) ((unsigned int*)(wsb + U32_B))[idx] = 0u;
}

__global__ __launch_bounds__(THREADS, 2)
void rnn_persist_kernel(const float* __restrict__ x,
                        const float* __restrict__ W_ih,
                        const float* __restrict__ b_ih,
                        const float* __restrict__ b_hh,
                        const float* __restrict__ fc_W,
                        const float* __restrict__ fc_b,
                        const float* __restrict__ c0,
                        char* __restrict__ wsb,
                        float* __restrict__ out) {
    __shared__ float smem[L_TOT];
    char* ldsst = (char*)smem;          // staging at byte 0 (32 KB)

    const int wg  = blockIdx.x;
    const int cl  = wg & 15;            // cluster -> XCD cl&7 under round-robin
    const int wl  = wg >> 4;            // 0..31
    const int j0  = wl * 16;
    const int nb0 = cl * 32;
    const int tid = threadIdx.x;
    const int lane = tid & 63;
    const int rb   = tid >> 6;          // wave id = row-tile (gate)
    const int m    = lane & 15;
    const int g    = lane >> 4;

    unsigned int* flags = (unsigned int*)(wsb + U32_B);        // [cl*32 + wl]
    unsigned int* ctr   = (unsigned int*)(wsb + U32_B + 3072);
    unsigned int* xccb  = (unsigned int*)(wsb + U32_B + 4096); // [wg]

    // ---- one-time: constants to LDS ----
    {
        int u = tid >> 5, b = tid & 31;
        smem[L_C + u * 32 + b]       = c0[j0 + u];
        smem[L_C + (u + 8) * 32 + b] = c0[j0 + 8 + u];
        if (tid < 64) {
            int gt = tid >> 4, u2 = tid & 15;
            smem[L_BIAS + tid] = b_ih[gt*512 + wl*16 + u2] + b_hh[gt*512 + wl*16 + u2];
        }
        for (int i = tid; i < 64 * DD; i += THREADS) {
            int r = i / DD, d = i - r * DD;
            int gt = r >> 4, u2 = r & 15;
            smem[L_WIH + r * 10 + d] = W_ih[(gt*512 + wl*16 + u2) * DD + d];
        }
    }

    // ---- one-time: W A-fragments into registers (hi + lo) ----
    s8v wAh[16], wAl[16];
    {
        const char* base = wsb + (unsigned)(((wl*4 + rb)*16)*64 + lane)*16u;
#pragma unroll
        for (int kt = 0; kt < 16; ++kt) {
            wAh[kt] = *(const s8v*)(base + WF_HI_B + kt*1024);
            wAl[kt] = *(const s8v*)(base + WF_LO_B + kt*1024);
        }
    }

    // ---- startup: publish XCD id, grid barrier, co-location check ----
    if (tid == 0) {
        unsigned xcc;
        asm volatile("s_getreg_b32 %0, hwreg(HW_REG_XCC_ID, 0, 32)" : "=s"(xcc));
        __hip_atomic_store(xccb + wg, xcc + 1u, __ATOMIC_RELAXED, __HIP_MEMORY_SCOPE_AGENT);
        __hip_atomic_fetch_add(ctr, 1u, __ATOMIC_RELEASE, __HIP_MEMORY_SCOPE_AGENT);
        while (__hip_atomic_load(ctr, __ATOMIC_RELAXED, __HIP_MEMORY_SCOPE_AGENT) < NWG)
            __builtin_amdgcn_s_sleep(8);
    }
    __syncthreads();
    {
        unsigned v = (tid < WPC)
            ? __hip_atomic_load(xccb + tid * NCL + cl, __ATOMIC_RELAXED,
                                __HIP_MEMORY_SCOPE_AGENT) : 0u;
        unsigned v0 = __shfl(v, 0, 64);
        bool ok = (tid >= WPC) || (v != 0u && v == v0);
        unsigned long long mk = __ballot(ok);
        if (tid == 0) smem[L_MISC] = (mk == ~0ull) ? 1.0f : 0.0f;
    }
    __syncthreads();
    const bool fast = (smem[L_MISC] != 0.0f);

    const int cw = tid >> 5;           // cell: units {cw, cw+8}
    const int cb = tid & 31;           // cell: batch
    const int fg = tid >> 4, fl = tid & 15;
    const int fgc = (fg < DD) ? fg : 0;

    for (int s = 0; s < NSTEP; ++s) {
        const int par = s & 1;
        const char* hsrc = wsb + HFRAG_B + (unsigned)(par*16 + cl) * 65536u;
        unsigned int* flg = flags + cl * 32;
        const bool dec = (s >= TP1 + 1);

        // ---- A. step wait: per-lane ATOMIC poll (coherence-point read; sc0 is stale-prone) ----
        if (s > 0) {
            if (tid < WPC) {
                for (;;) {
                    unsigned v = __hip_atomic_load(flg + tid, __ATOMIC_RELAXED,
                                                   __HIP_MEMORY_SCOPE_AGENT);
                    if (__all((int)(v >= (unsigned)s))) break;
                    __builtin_amdgcn_s_sleep(2);
                }
            }
            __syncthreads();
            if (fast) __builtin_amdgcn_fence(__ATOMIC_ACQUIRE, "workgroup");
            else      __builtin_amdgcn_fence(__ATOMIC_ACQUIRE, "agent");
        }

        // ---- B. issue ALL 16 hfrag loads (whole step) ----
        i4v hb[16];
#pragma unroll
        for (int c = 0; c < 16; ++c)
            ld16i(hb[c], hsrc + c*4096 + tid*16);

        // ---- C. x load (encode; plain, compiler-managed) ----
        float xv[DD];
        if (s < TP1) {
            const float* xp = x + (size_t)(nb0 + cb) * (TP1 * DD) + s * DD;
#pragma unroll
            for (int d = 0; d < DD; ++d) xv[d] = xp[d];
        }

        // ---- D. one vm stall for the whole step; stage phase A (kt 0-7) ----
        wait_vm0_mem();
#pragma unroll
        for (int c = 0; c < 8; ++c)
            *(i4v*)(ldsst + c*4096 + tid*16) = hb[c];
        lgkm0_bar();

        // ---- E. GEMM phase A: kt 0-7 ----
        f4v acc0 = {0.f,0.f,0.f,0.f}, acc1 = {0.f,0.f,0.f,0.f};
#pragma unroll
        for (int kt = 0; kt < 8; ++kt) {
            const char* bb = ldsst + kt*4096;
            s8v bh0 = *(const s8v*)(bb + g*512        + m*16);
            s8v bh1 = *(const s8v*)(bb + g*512        + m*16 + 256);
            s8v bl0 = *(const s8v*)(bb + 2048 + g*512 + m*16);
            s8v bl1 = *(const s8v*)(bb + 2048 + g*512 + m*16 + 256);
            acc0 = __builtin_amdgcn_mfma_f32_16x16x32_bf16(wAh[kt], bh0, acc0, 0,0,0);
            acc1 = __builtin_amdgcn_mfma_f32_16x16x32_bf16(wAh[kt], bh1, acc1, 0,0,0);
            acc0 = __builtin_amdgcn_mfma_f32_16x16x32_bf16(wAl[kt], bh0, acc0, 0,0,0);
            acc1 = __builtin_amdgcn_mfma_f32_16x16x32_bf16(wAl[kt], bh1, acc1, 0,0,0);
            acc0 = __builtin_amdgcn_mfma_f32_16x16x32_bf16(wAh[kt], bl0, acc0, 0,0,0);
            acc1 = __builtin_amdgcn_mfma_f32_16x16x32_bf16(wAh[kt], bl1, acc1, 0,0,0);
        }
        lgkm0_bar();   // all waves done reading phase A

        // ---- F. stage phase B (kt 8-15) into the same 32 KB ----
#pragma unroll
        for (int c = 0; c < 8; ++c)
            *(i4v*)(ldsst + c*4096 + tid*16) = hb[c + 8];

        // ---- G. fc hrow loads (decode; wave-uniform) — consumed at step end, hb now dead ----
        f4v q0,q1,q2,q3,q4,q5,q6,q7;
        if (dec) {
            const char* hp = wsb + HROW_B + (unsigned)(par*16 + cl)*65536u
                             + (unsigned)(wl*512 + fl*32)*4u;
            ld16f(q0, hp);      ld16f(q1, hp+16);  ld16f(q2, hp+32);  ld16f(q3, hp+48);
            ld16f(q4, hp+64);   ld16f(q5, hp+80);  ld16f(q6, hp+96);  ld16f(q7, hp+112);
        }
        lgkm0_bar();

        // ---- H. GEMM phase B ----
#pragma unroll
        for (int kt = 8; kt < 16; ++kt) {
            const char* bb = ldsst + (kt-8)*4096;
            s8v bh0 = *(const s8v*)(bb + g*512        + m*16);
            s8v bh1 = *(const s8v*)(bb + g*512        + m*16 + 256);
            s8v bl0 = *(const s8v*)(bb + 2048 + g*512 + m*16);
            s8v bl1 = *(const s8v*)(bb + 2048 + g*512 + m*16 + 256);
            acc0 = __builtin_amdgcn_mfma_f32_16x16x32_bf16(wAh[kt], bh0, acc0, 0,0,0);
            acc1 = __builtin_amdgcn_mfma_f32_16x16x32_bf16(wAh[kt], bh1, acc1, 0,0,0);
            acc0 = __builtin_amdgcn_mfma_f32_16x16x32_bf16(wAl[kt], bh0, acc0, 0,0,0);
            acc1 = __builtin_amdgcn_mfma_f32_16x16x32_bf16(wAl[kt], bh1, acc1, 0,0,0);
            acc0 = __builtin_amdgcn_mfma_f32_16x16x32_bf16(wAh[kt], bl0, acc0, 0,0,0);
            acc1 = __builtin_amdgcn_mfma_f32_16x16x32_bf16(wAh[kt], bl1, acc1, 0,0,0);
        }

        // ---- I. acc -> gates LDS (C/D: row = g*4 + reg, col = m) ----
        {
            float* gp = smem + L_GATES + (rb*16 + g*4) * GSTR + m;
            gp[0*GSTR]      = acc0.x; gp[1*GSTR]      = acc0.y;
            gp[2*GSTR]      = acc0.z; gp[3*GSTR]      = acc0.w;
            gp[0*GSTR + 16] = acc1.x; gp[1*GSTR + 16] = acc1.y;
            gp[2*GSTR + 16] = acc1.z; gp[3*GSTR + 16] = acc1.w;
        }
        lgkm0_bar();

        // ---- J. LSTM cell: units {cw, cw+8}, batch cb ----
        {
#pragma unroll
            for (int half = 0; half < 2; ++half) {
                const int u = cw + half * 8;
                float vi = smem[L_GATES + (u) * GSTR + cb]      + smem[L_BIAS + u];
                float vf = smem[L_GATES + (16 + u) * GSTR + cb] + smem[L_BIAS + 16 + u];
                float vg = smem[L_GATES + (32 + u) * GSTR + cb] + smem[L_BIAS + 32 + u];
                float vo = smem[L_GATES + (48 + u) * GSTR + cb] + smem[L_BIAS + 48 + u];
                if (s < TP1) {
                    float di = 0.f, df = 0.f, dg = 0.f, dq = 0.f;
#pragma unroll
                    for (int d = 0; d < DD; ++d) {
                        di += xv[d] * smem[L_WIH + (u) * 10 + d];
                        df += xv[d] * smem[L_WIH + (16 + u) * 10 + d];
                        dg += xv[d] * smem[L_WIH + (32 + u) * 10 + d];
                        dq += xv[d] * smem[L_WIH + (48 + u) * 10 + d];
                    }
                    vi += di; vf += df; vg += dg; vo += dq;
                }
                float c_old = smem[L_C + u * 32 + cb];
                float si = sigmoidf_(vi), sf = sigmoidf_(vf), so = sigmoidf_(vo);
                float tg = tanhf_(vg);
                float cn = sf * c_old + si * tg;
                smem[L_C + u * 32 + cb] = cn;
                smem[L_HNEW + u * 32 + cb] = so * tanhf_(cn);
            }
        }
        lgkm0_bar();

        // ---- K. hrow write + pack hfrag for next step ----
        {
            float* hrp = (float*)(wsb + HROW_B + (unsigned)((par^1)*16 + cl)*65536u);
            const int kl = tid & 15, nl0 = tid >> 4;
#pragma unroll
            for (int i = 0; i < 2; ++i) {
                const int nl = nl0 + i * 16;
                hrp[nl * 512 + j0 + kl] = smem[L_HNEW + kl * 32 + nl];
            }
        }
        if (tid < 128) {
            const int col = tid & 31, jblk = (tid >> 5) & 1, arr = (tid >> 6) & 1;
            const int jb = wl * 2 + jblk;
            const int kt = jb >> 2, gg = jb & 3;
            s8v v;
#pragma unroll
            for (int i = 0; i < 8; ++i) {
                float f = smem[L_HNEW + (jblk * 8 + i) * 32 + col];
                unsigned short hi = bf16hi_rne(f);
                unsigned short w = hi;
                if (arr) {
                    float fh = __uint_as_float(((unsigned)hi) << 16);
                    w = bf16hi_rne(f - fh);
                }
                v[i] = (short)w;
            }
            char* dst = wsb + HFRAG_B + (unsigned)((par^1)*16 + cl)*65536u
                        + (unsigned)(kt*4096 + arr*2048 + gg*512 + col*16);
            *(s8v*)dst = v;
        }
        wait_vm0_mem();   // drains hrow/pack stores AND outstanding q loads
        __syncthreads();

        // ---- L. signal ----
        if (tid == 0) {
            if (fast) {
                __hip_atomic_store(flg + wl, (unsigned)(s + 1),
                                   __ATOMIC_RELAXED, __HIP_MEMORY_SCOPE_AGENT);
            } else {
                __builtin_amdgcn_fence(__ATOMIC_RELEASE, "agent");
                __hip_atomic_store(flg + wl, (unsigned)(s + 1),
                                   __ATOMIC_RELEASE, __HIP_MEMORY_SCOPE_AGENT);
            }
        }

        // ---- M. fc compute for h(s) (decode): out[:, s-258, :] ----
        if (dec && fg < DD) {
            const f4v* wv = (const f4v*)(fc_W + fgc * HH + fl * 32);
            float acc = 0.f;
            acc += q0.x*wv[0].x + q0.y*wv[0].y + q0.z*wv[0].z + q0.w*wv[0].w;
            acc += q1.x*wv[1].x + q1.y*wv[1].y + q1.z*wv[1].z + q1.w*wv[1].w;
            acc += q2.x*wv[2].x + q2.y*wv[2].y + q2.z*wv[2].z + q2.w*wv[2].w;
            acc += q3.x*wv[3].x + q3.y*wv[3].y + q3.z*wv[3].z + q3.w*wv[3].w;
            acc += q4.x*wv[4].x + q4.y*wv[4].y + q4.z*wv[4].z + q4.w*wv[4].w;
            acc += q5.x*wv[5].x + q5.y*wv[5].y + q5.z*wv[5].z + q5.w*wv[5].w;
            acc += q6.x*wv[6].x + q6.y*wv[6].y + q6.z*wv[6].z + q6.w*wv[6].w;
            acc += q7.x*wv[7].x + q7.y*wv[7].y + q7.z*wv[7].z + q7.w*wv[7].w;
            acc += __shfl_down(acc, 8, 16);
            acc += __shfl_down(acc, 4, 16);
            acc += __shfl_down(acc, 2, 16);
            acc += __shfl_down(acc, 1, 16);
            if (fl == 0)
                out[(size_t)(nb0 + wl) * (TT * DD) + (s - (TP1 + 1)) * DD + fgc] =
                    1.0f / (1.0f + __expf(-(acc + fc_b[fgc])));
        }
    }

    // ---- tail fc: td = 255 from h(513) ----
    {
        if (tid < WPC) {
            for (;;) {
                unsigned v = __hip_atomic_load(flags + cl * 32 + tid,
                                               __ATOMIC_RELAXED, __HIP_MEMORY_SCOPE_AGENT);
                if (__all((int)(v >= (unsigned)NSTEP))) break;
                __builtin_amdgcn_s_sleep(2);
            }
        }
        __syncthreads();
        if (fast) __builtin_amdgcn_fence(__ATOMIC_ACQUIRE, "workgroup");
        else      __builtin_amdgcn_fence(__ATOMIC_ACQUIRE, "agent");

        if (fg < DD) {
            const char* hp = wsb + HROW_B + (unsigned)((NSTEP & 1)*16 + cl)*65536u
                             + (unsigned)(wl*512 + fl*32)*4u;
            f4v q0,q1,q2,q3,q4,q5,q6,q7;
            ld16f(q0, hp);      ld16f(q1, hp+16);  ld16f(q2, hp+32);  ld16f(q3, hp+48);
            ld16f(q4, hp+64);   ld16f(q5, hp+80);  ld16f(q6, hp+96);  ld16f(q7, hp+112);
            const f4v* wv = (const f4v*)(fc_W + fgc * HH + fl * 32);
            wait_vm0_8f(q0,q1,q2,q3,q4,q5,q6,q7);
            float acc = 0.f;
            acc += q0.x*wv[0].x + q0.y*wv[0].y + q0.z*wv[0].z + q0.w*wv[0].w;
            acc += q1.x*wv[1].x + q1.y*wv[1].y + q1.z*wv[1].z + q1.w*wv[1].w;
            acc += q2.x*wv[2].x + q2.y*wv[2].y + q2.z*wv[2].z + q2.w*wv[2].w;
            acc += q3.x*wv[3].x + q3.y*wv[3].y + q3.z*wv[3].z + q3.w*wv[3].w;
            acc += q4.x*wv[4].x + q4.y*wv[4].y + q4.z*wv[4].z + q4.w*wv[4].w;
            acc += q5.x*wv[5].x + q5.y*wv[5].y + q5.z*wv[5].z + q5.w*wv[5].w;
            acc += q6.x*wv[6].x + q6.y*wv[6].y + q6.z*wv[6].z + q6.w*wv[6].w;
            acc += q7.x*wv[7].x + q7.y*wv[7].y + q7.z*wv[7].z + q7.w*wv[7].w;
            acc += __shfl_down(acc, 8, 16);
            acc += __shfl_down(acc, 4, 16);
            acc += __shfl_down(acc, 2, 16);
            acc += __shfl_down(acc, 1, 16);
            if (fl == 0)
                out[(size_t)(nb0 + wl) * (TT * DD) + 255 * DD + fgc] =
                    1.0f / (1.0f + __expf(-(acc + fc_b[fgc])));
        }
    }
}

extern "C" void kernel_launch(void* const* d_in, const int* in_sizes, int n_in,
                              void* d_out, int out_size, void* d_ws, size_t ws_size,
                              hipStream_t stream) {
    (void)in_sizes; (void)n_in; (void)out_size; (void)ws_size;
    const float* x    = (const float*)d_in[0];
    const float* W_ih = (const float*)d_in[1];
    const float* W_hh = (const float*)d_in[2];
    const float* b_ih = (const float*)d_in[3];
    const float* b_hh = (const float*)d_in[4];
    const float* fc_W = (const float*)d_in[5];
    const float* fc_b = (const float*)d_in[6];
    const float* h0   = (const float*)d_in[7];
    const float* c0   = (const float*)d_in[8];
    float* out = (float*)d_out;
    char*  wsb = (char*)d_ws;

    hipLaunchKernelGGL(rnn_init_kernel, dim3(4096), dim3(256), 0, stream,
                       W_hh, h0, wsb);
    hipLaunchKernelGGL(rnn_persist_kernel, dim3(NWG), dim3(THREADS), 0, stream,
                       x, W_ih, b_ih, b_hh, fc_W, fc_b, c0, wsb, out);
}